// Round 1
// baseline (1167.113 us; speedup 1.0000x reference)
//
#include <hip/hip_runtime.h>
#include <hip/hip_bf16.h>
#include <math.h>

// Problem constants (ModernBERT attention)
#define BATCH 4
#define SEQ   2048
#define DMODEL 768
#define NHEADS 12
#define HDIM  64
#define WIN   64          // window each side
#define QKV_LD 2304       // 3*DMODEL

// ---------------------------------------------------------------------------
// Generic fp32 NT GEMM: C[m,n] = sum_k A[m*lda+k] * B[n*ldb+k]
// BM=BN=64, BK=16, 256 threads, 4x4 micro-tile per thread.
// ---------------------------------------------------------------------------
__global__ void gemm_nt_f32(const float* __restrict__ A, const float* __restrict__ B,
                            float* __restrict__ C, int lda, int ldb, int ldc, int K) {
    __shared__ float As[64][17];
    __shared__ float Bs[64][17];

    const int tid = threadIdx.x;
    const int tx = tid & 15;        // 0..15 (cols)
    const int ty = tid >> 4;        // 0..15 (rows)
    const int m0 = blockIdx.y * 64;
    const int n0 = blockIdx.x * 64;

    const int loadRow = tid >> 2;        // 0..63
    const int loadK   = (tid & 3) * 4;   // 0,4,8,12

    float acc[4][4];
#pragma unroll
    for (int i = 0; i < 4; i++)
#pragma unroll
        for (int j = 0; j < 4; j++) acc[i][j] = 0.f;

    for (int k0 = 0; k0 < K; k0 += 16) {
        float4 a4 = *(const float4*)(A + (size_t)(m0 + loadRow) * lda + k0 + loadK);
        float4 b4 = *(const float4*)(B + (size_t)(n0 + loadRow) * ldb + k0 + loadK);
        __syncthreads();   // protect previous iteration's reads
        As[loadRow][loadK + 0] = a4.x; As[loadRow][loadK + 1] = a4.y;
        As[loadRow][loadK + 2] = a4.z; As[loadRow][loadK + 3] = a4.w;
        Bs[loadRow][loadK + 0] = b4.x; Bs[loadRow][loadK + 1] = b4.y;
        Bs[loadRow][loadK + 2] = b4.z; Bs[loadRow][loadK + 3] = b4.w;
        __syncthreads();
#pragma unroll
        for (int k = 0; k < 16; k++) {
            float ar[4], br[4];
#pragma unroll
            for (int i = 0; i < 4; i++) ar[i] = As[ty * 4 + i][k];
#pragma unroll
            for (int j = 0; j < 4; j++) br[j] = Bs[tx * 4 + j][k];
#pragma unroll
            for (int i = 0; i < 4; i++)
#pragma unroll
                for (int j = 0; j < 4; j++) acc[i][j] += ar[i] * br[j];
        }
    }

#pragma unroll
    for (int i = 0; i < 4; i++) {
        float4 o = make_float4(acc[i][0], acc[i][1], acc[i][2], acc[i][3]);
        *(float4*)(C + (size_t)(m0 + ty * 4 + i) * ldc + n0 + tx * 4) = o;
    }
}

// ---------------------------------------------------------------------------
// RoPE applied in place to q and k regions of qkv [B*T, 2304].
// Pairing (j, j+32) rotated by angle t * theta^(-j/32); output kept in the
// SAME slots (no interleave permutation) — valid because q,k get identical
// permutation and only q.k dot products are consumed.
// One thread per (b,t,head,j); handles both q and k.
// ---------------------------------------------------------------------------
__global__ void rope_kernel(float* qkv) {
    int idx = blockIdx.x * blockDim.x + threadIdx.x;   // B*T*NHEADS*32
    int j = idx & 31;
    int n = (idx >> 5) % NHEADS;
    int m = idx / (32 * NHEADS);                       // b*T + t
    int t = m & (SEQ - 1);

    // inv_freq = 10000^(-j/32) = exp2(-j/32 * log2(10000))
    const float L2T_OVER_32 = 13.287712379549449f / 32.0f;
    float inv = exp2f(-(float)j * L2T_OVER_32);
    float ang = (float)t * inv;
    float s, c;
    sincosf(ang, &s, &c);

    size_t base = (size_t)m * QKV_LD + n * HDIM + j;
    // q
    {
        float x0 = qkv[base], x1 = qkv[base + 32];
        qkv[base]      = x0 * c - x1 * s;
        qkv[base + 32] = x0 * s + x1 * c;
    }
    // k (offset +768)
    {
        float x0 = qkv[base + DMODEL], x1 = qkv[base + DMODEL + 32];
        qkv[base + DMODEL]      = x0 * c - x1 * s;
        qkv[base + DMODEL + 32] = x0 * s + x1 * c;
    }
}

// ---------------------------------------------------------------------------
// Sliding-window attention. One block per (b, head, 16-query tile).
// K tile (<=144 keys) staged in LDS; scores+softmax in LDS; PV from global.
// Attention output is written into the q-region of qkv (safe: each block
// reads exactly the q rows it overwrites, K/V regions untouched).
// ---------------------------------------------------------------------------
__global__ void attn_kernel(float* qkv, const int* __restrict__ mask) {
    const int tile = blockIdx.x;       // 0..127
    const int n = blockIdx.y;          // head
    const int b = blockIdx.z;
    const int q0 = tile * 16;
    const int klo = max(0, q0 - WIN);
    const int khi = min(SEQ, q0 + 16 + WIN);
    const int nk = khi - klo;          // <= 144

    __shared__ float Qs[16][65];
    __shared__ float Ks[144][65];
    __shared__ float S[16][145];

    const int tid = threadIdx.x;
    const size_t rowbase = (size_t)(b * SEQ) * QKV_LD + n * HDIM;

    // load Q tile (16 x 64)
    {
        int qi = tid >> 4, h = (tid & 15) * 4;
        float4 v = *(const float4*)(qkv + rowbase + (size_t)(q0 + qi) * QKV_LD + h);
        Qs[qi][h] = v.x; Qs[qi][h + 1] = v.y; Qs[qi][h + 2] = v.z; Qs[qi][h + 3] = v.w;
    }
    // load K tile (nk x 64)
    for (int e = tid * 4; e < nk * 64; e += 1024) {
        int kj = e >> 6, h = e & 63;
        float4 v = *(const float4*)(qkv + rowbase + (size_t)(klo + kj) * QKV_LD + DMODEL + h);
        Ks[kj][h] = v.x; Ks[kj][h + 1] = v.y; Ks[kj][h + 2] = v.z; Ks[kj][h + 3] = v.w;
    }
    __syncthreads();

    // scores: 16*144 pairs over 256 threads (9 iters)
    const int* mb = mask + b * SEQ;
    for (int p = tid; p < 16 * 144; p += 256) {
        int qi = p / 144, kj = p % 144;
        if (kj < nk) {
            int q = q0 + qi, k = klo + kj;
            float s = -1e30f;
            if (abs(q - k) <= WIN && mb[q] != 0 && mb[k] != 0) {
                float a = 0.f;
#pragma unroll
                for (int h = 0; h < 64; h++) a += Qs[qi][h] * Ks[kj][h];
                s = a * 0.125f;   // 1/sqrt(64)
            }
            S[qi][kj] = s;
        }
    }
    __syncthreads();

    // softmax per query row (threads 0..15, serial over <=144)
    if (tid < 16) {
        float m = -1e30f;
        for (int k = 0; k < nk; k++) m = fmaxf(m, S[tid][k]);
        float sum = 0.f;
        for (int k = 0; k < nk; k++) { float e = __expf(S[tid][k] - m); S[tid][k] = e; sum += e; }
        float r = 1.0f / sum;
        for (int k = 0; k < nk; k++) S[tid][k] *= r;
    }
    __syncthreads();

    // output: out[qi][h..h+3] = sum_k p * v  ; write into q-region slot
    {
        int qi = tid >> 4, h = (tid & 15) * 4;
        float4 acc = make_float4(0.f, 0.f, 0.f, 0.f);
        for (int k = 0; k < nk; k++) {
            float p = S[qi][k];
            float4 v = *(const float4*)(qkv + rowbase + (size_t)(klo + k) * QKV_LD + 2 * DMODEL + h);
            acc.x += p * v.x; acc.y += p * v.y; acc.z += p * v.z; acc.w += p * v.w;
        }
        *(float4*)(qkv + rowbase + (size_t)(q0 + qi) * QKV_LD + h) = acc;
    }
}

// ---------------------------------------------------------------------------
extern "C" void kernel_launch(void* const* d_in, const int* in_sizes, int n_in,
                              void* d_out, int out_size, void* d_ws, size_t ws_size,
                              hipStream_t stream) {
    const float* hidden = (const float*)d_in[0];
    const int*   mask   = (const int*)d_in[1];
    const float* Wqkv   = (const float*)d_in[2];
    const float* Wo     = (const float*)d_in[3];
    float* out = (float*)d_out;

    float* qkv = (float*)d_ws;                     // [8192, 2304] = 75.5 MB

    const int M = BATCH * SEQ;                     // 8192

    // 1) QKV projection: qkv[m,e] = sum_d h[m,d] * Wqkv[e,d]
    {
        dim3 grid(QKV_LD / 64, M / 64);            // (36, 128)
        gemm_nt_f32<<<grid, 256, 0, stream>>>(hidden, Wqkv, qkv,
                                              DMODEL, DMODEL, QKV_LD, DMODEL);
    }
    // 2) RoPE on q and k (in place)
    {
        int total = M * NHEADS * 32;               // 3,145,728
        rope_kernel<<<total / 256, 256, 0, stream>>>(qkv);
    }
    // 3) Sliding-window attention; writes attn into q-region of qkv
    {
        dim3 grid(SEQ / 16, NHEADS, BATCH);        // (128, 12, 4)
        attn_kernel<<<grid, 256, 0, stream>>>(qkv, mask);
    }
    // 4) Output projection: out[m,e] = sum_d attn[m,d] * Wo[e,d]
    //    attn lives at qkv with lda = 2304 (q-region slots)
    {
        dim3 grid(DMODEL / 64, M / 64);            // (12, 128)
        gemm_nt_f32<<<grid, 256, 0, stream>>>(qkv, Wo, out,
                                              QKV_LD, DMODEL, DMODEL, DMODEL);
    }
}

// Round 2
// 262.473 us; speedup vs baseline: 4.4466x; 4.4466x over previous
//
#include <hip/hip_runtime.h>
#include <hip/hip_bf16.h>
#include <math.h>

// Problem constants (ModernBERT attention)
#define BATCH 4
#define SEQ   2048
#define DMODEL 768
#define NHEADS 12
#define HDIM  64
#define WIN   64          // window each side
#define QKV_LD 2304       // 3*DMODEL

typedef __attribute__((ext_vector_type(8))) short bf16x8;  // 8 bf16 = 4 VGPRs
typedef __attribute__((ext_vector_type(4))) float f32x4;

typedef __attribute__((address_space(1))) const unsigned int guint;
typedef __attribute__((address_space(3))) unsigned int luint;

__device__ inline void gl_lds16(const __hip_bfloat16* g, __hip_bfloat16* l) {
    // async global->LDS, 16 bytes/lane; LDS dest = wave-uniform base + lane*16
    __builtin_amdgcn_global_load_lds((guint*)g, (luint*)l, 16, 0, 0);
}

__device__ inline float b2f(unsigned short u) {
    unsigned int x = ((unsigned int)u) << 16;
    union { unsigned int i; float f; } c; c.i = x; return c.f;
}

__device__ inline void store_out(float* p, float v) { *p = v; }
__device__ inline void store_out(__hip_bfloat16* p, float v) { *p = __float2bfloat16(v); }

// ---------------------------------------------------------------------------
// cast fp32 -> bf16, 4 elems/thread
// ---------------------------------------------------------------------------
__global__ __launch_bounds__(256) void cast_f32_bf16(const float* __restrict__ in,
                                                     __hip_bfloat16* __restrict__ out, int n4) {
    int i = blockIdx.x * blockDim.x + threadIdx.x;
    if (i < n4) {
        float4 v = ((const float4*)in)[i];
        union { ushort4 u; __hip_bfloat16 h[4]; } o;
        o.h[0] = __float2bfloat16(v.x); o.h[1] = __float2bfloat16(v.y);
        o.h[2] = __float2bfloat16(v.z); o.h[3] = __float2bfloat16(v.w);
        ((ushort4*)out)[i] = o.u;
    }
}

// ---------------------------------------------------------------------------
// bf16 MFMA NT GEMM: C[m,n] = sum_k A[m*lda+k]*B[n*ldb+k]
// BM=BN=128, BK=32, 256 threads = 4 waves, each wave 64x64 via 4x4 MFMA frags.
// m97-style: global_load_lds width-16 staging, single-buffered LDS.
// ---------------------------------------------------------------------------
template <typename OutT>
__global__ __launch_bounds__(256) void gemm_nt_bf16(const __hip_bfloat16* __restrict__ A,
                                                    const __hip_bfloat16* __restrict__ B,
                                                    OutT* __restrict__ C,
                                                    int lda, int ldb, int ldc, int K) {
    __shared__ __align__(16) __hip_bfloat16 As[128 * 32];   // 8 KB, row-major [128][32]
    __shared__ __align__(16) __hip_bfloat16 Bs[128 * 32];   // 8 KB

    const int tid  = threadIdx.x;
    const int lane = tid & 63;
    const int wave = tid >> 6;
    const int wr   = wave >> 1;     // wave row (0..1)
    const int wc   = wave & 1;      // wave col (0..1)
    const int fr   = lane & 15;     // fragment row/col index
    const int quad = lane >> 4;     // 0..3
    const int m0   = blockIdx.y * 128;
    const int n0   = blockIdx.x * 128;

    f32x4 acc[4][4];
#pragma unroll
    for (int i = 0; i < 4; i++)
#pragma unroll
        for (int j = 0; j < 4; j++) acc[i][j] = (f32x4){0.f, 0.f, 0.f, 0.f};

    for (int k0 = 0; k0 < K; k0 += 32) {
        __syncthreads();   // LDS reads of previous iter done before overwrite
        // stage A,B tiles: 4096 bf16 each; per wave-issue 64 lanes x 8 elems
#pragma unroll
        for (int c = 0; c < 2; c++) {
            int e = (wave * 2 + c) * 512 + lane * 8;   // elem index in tile
            int row = e >> 5, col = e & 31;
            gl_lds16(A + (size_t)(m0 + row) * lda + k0 + col, As + e);
            gl_lds16(B + (size_t)(n0 + row) * ldb + k0 + col, Bs + e);
        }
        __syncthreads();   // compiler inserts vmcnt(0) drain before barrier

        bf16x8 af[4], bf_[4];
#pragma unroll
        for (int mi = 0; mi < 4; mi++)
            af[mi] = *(const bf16x8*)(As + (wr * 64 + mi * 16 + fr) * 32 + quad * 8);
#pragma unroll
        for (int ni = 0; ni < 4; ni++)
            bf_[ni] = *(const bf16x8*)(Bs + (wc * 64 + ni * 16 + fr) * 32 + quad * 8);
#pragma unroll
        for (int mi = 0; mi < 4; mi++)
#pragma unroll
            for (int ni = 0; ni < 4; ni++)
                acc[mi][ni] = __builtin_amdgcn_mfma_f32_16x16x32_bf16(af[mi], bf_[ni], acc[mi][ni], 0, 0, 0);
    }

    // epilogue: C/D layout col=lane&15, row=quad*4+reg
#pragma unroll
    for (int mi = 0; mi < 4; mi++)
#pragma unroll
        for (int ni = 0; ni < 4; ni++) {
            f32x4 v = acc[mi][ni];
            int gc = n0 + wc * 64 + ni * 16 + fr;
            size_t rbase = (size_t)(m0 + wr * 64 + mi * 16 + quad * 4);
#pragma unroll
            for (int r = 0; r < 4; r++)
                store_out(&C[(rbase + r) * ldc + gc], v[r]);
        }
}

// ---------------------------------------------------------------------------
// RoPE in place on bf16 qkv: pairs (j, j+32) rotated, no permutation (valid
// since q and k get identical treatment and only q.k is consumed).
// ---------------------------------------------------------------------------
__global__ __launch_bounds__(256) void rope_kernel(__hip_bfloat16* qkv) {
    int idx = blockIdx.x * blockDim.x + threadIdx.x;   // B*T*NHEADS*32
    int j = idx & 31;
    int n = (idx >> 5) % NHEADS;
    int m = idx / (32 * NHEADS);
    int t = m & (SEQ - 1);

    const float L2T_OVER_32 = 13.287712379549449f / 32.0f;  // log2(10000)/32
    float inv = exp2f(-(float)j * L2T_OVER_32);
    float ang = (float)t * inv;
    float s, c;
    sincosf(ang, &s, &c);

    size_t base = (size_t)m * QKV_LD + n * HDIM + j;
    {
        float x0 = __bfloat162float(qkv[base]), x1 = __bfloat162float(qkv[base + 32]);
        qkv[base]      = __float2bfloat16(x0 * c - x1 * s);
        qkv[base + 32] = __float2bfloat16(x0 * s + x1 * c);
    }
    {
        float x0 = __bfloat162float(qkv[base + DMODEL]), x1 = __bfloat162float(qkv[base + DMODEL + 32]);
        qkv[base + DMODEL]      = __float2bfloat16(x0 * c - x1 * s);
        qkv[base + DMODEL + 32] = __float2bfloat16(x0 * s + x1 * c);
    }
}

// ---------------------------------------------------------------------------
// Sliding-window attention, one block per (b, head, 16-query tile).
// QK^T via MFMA (bf16), parallel softmax, fp32 PV from bf16 LDS V.
// Writes bf16 attn output [B*T, 768].
// ---------------------------------------------------------------------------
#define KPAD 72   // 72*2B = 144B = 9*16B -> conflict-free b128 fragment reads

__global__ __launch_bounds__(256) void attn_kernel(const __hip_bfloat16* __restrict__ qkv,
                                                   const int* __restrict__ mask,
                                                   __hip_bfloat16* __restrict__ attn) {
    const int tile = blockIdx.x;
    const int n = blockIdx.y;
    const int b = blockIdx.z;
    const int q0 = tile * 16;
    const int klo = max(0, q0 - WIN);
    const int khi = min(SEQ, q0 + 16 + WIN);
    const int nk = khi - klo;          // multiple of 16, <= 144
    const int nt = nk >> 4;            // # of 16-key tiles

    __shared__ __align__(16) __hip_bfloat16 Qs[16 * KPAD];    // 2.3 KB
    __shared__ __align__(16) __hip_bfloat16 Ks[144 * KPAD];   // 20.7 KB
    __shared__ __align__(16) __hip_bfloat16 Vs[144 * 64];     // 18.4 KB (unpadded: PV reads broadcast)
    __shared__ float S[16][145];                              // 9.3 KB
    __shared__ float red[16][16];

    const int tid  = threadIdx.x;
    const int lane = tid & 63;
    const int wave = tid >> 6;
    const int fr   = lane & 15;
    const int quad = lane >> 4;
    const size_t rowbase = (size_t)(b * SEQ) * QKV_LD + n * HDIM;

    // stage Q (16x64)
    {
        int row = tid >> 4, col4 = (tid & 15) * 4;
        ushort4 v = *(const ushort4*)(qkv + rowbase + (size_t)(q0 + row) * QKV_LD + col4);
        *(ushort4*)(Qs + row * KPAD + col4) = v;
    }
    // stage K and V (nk x 64 each), 8 bf16 per thread-iter
    for (int e = tid * 8; e < nk * 64; e += 256 * 8) {
        int row = e >> 6, col8 = e & 63;
        uint4 kv = *(const uint4*)(qkv + rowbase + (size_t)(klo + row) * QKV_LD + DMODEL + col8);
        *(uint4*)(Ks + row * KPAD + col8) = kv;
        uint4 vv = *(const uint4*)(qkv + rowbase + (size_t)(klo + row) * QKV_LD + 2 * DMODEL + col8);
        *(uint4*)(Vs + row * 64 + col8) = vv;
    }
    __syncthreads();

    // QK^T via MFMA: wave w handles key tiles w, w+4, w+8
    bf16x8 aq[2];
#pragma unroll
    for (int kk = 0; kk < 2; kk++)
        aq[kk] = *(const bf16x8*)(Qs + fr * KPAD + kk * 32 + quad * 8);

    const int* mb = mask + b * SEQ;
    for (int t = wave; t < nt; t += 4) {
        f32x4 acc = (f32x4){0.f, 0.f, 0.f, 0.f};
#pragma unroll
        for (int kk = 0; kk < 2; kk++) {
            bf16x8 bk = *(const bf16x8*)(Ks + (t * 16 + fr) * KPAD + kk * 32 + quad * 8);
            acc = __builtin_amdgcn_mfma_f32_16x16x32_bf16(aq[kk], bk, acc, 0, 0, 0);
        }
        // C layout: col(key)=fr, row(query)=quad*4+r
        int kj = t * 16 + fr;
        int kg = klo + kj;
        int mk = mb[kg];
#pragma unroll
        for (int r = 0; r < 4; r++) {
            int qi = quad * 4 + r;
            int qg = q0 + qi;
            bool ok = (abs(qg - kg) <= WIN) && (mk != 0) && (mb[qg] != 0);
            S[qi][kj] = ok ? acc[r] * 0.125f : -1e30f;
        }
    }
    __syncthreads();

    // softmax: 16 threads per query row
    {
        const int row = tid >> 4, c = tid & 15;
        float mx = -1e30f;
        for (int k = c; k < nk; k += 16) mx = fmaxf(mx, S[row][k]);
        red[row][c] = mx;
        __syncthreads();
        if (c == 0) {
            float mm = -1e30f;
#pragma unroll
            for (int i = 0; i < 16; i++) mm = fmaxf(mm, red[row][i]);
            red[row][0] = mm;
        }
        __syncthreads();
        float mm = red[row][0];
        float sum = 0.f;
        for (int k = c; k < nk; k += 16) {
            float e = __expf(S[row][k] - mm);
            S[row][k] = e;
            sum += e;
        }
        __syncthreads();   // all S updates done before reusing red
        red[row][c] = sum;
        __syncthreads();
        if (c == 0) {
            float ss = 0.f;
#pragma unroll
            for (int i = 0; i < 16; i++) ss += red[row][i];
            red[row][0] = 1.0f / ss;
        }
        __syncthreads();
        float rs = red[row][0];
        for (int k = c; k < nk; k += 16) S[row][k] *= rs;
    }
    __syncthreads();

    // PV: thread (qi, h4) accumulates over nk keys
    {
        int qi = tid >> 4, h4 = (tid & 15) * 4;
        float a0 = 0.f, a1 = 0.f, a2 = 0.f, a3 = 0.f;
        for (int k = 0; k < nk; k++) {
            float p = S[qi][k];
            ushort4 v = *(const ushort4*)(Vs + k * 64 + h4);
            a0 += p * b2f(v.x); a1 += p * b2f(v.y);
            a2 += p * b2f(v.z); a3 += p * b2f(v.w);
        }
        union { ushort4 u; __hip_bfloat16 h[4]; } o;
        o.h[0] = __float2bfloat16(a0); o.h[1] = __float2bfloat16(a1);
        o.h[2] = __float2bfloat16(a2); o.h[3] = __float2bfloat16(a3);
        *(ushort4*)(attn + (size_t)(b * SEQ + q0 + qi) * DMODEL + n * HDIM + h4) = o.u;
    }
}

// ---------------------------------------------------------------------------
extern "C" void kernel_launch(void* const* d_in, const int* in_sizes, int n_in,
                              void* d_out, int out_size, void* d_ws, size_t ws_size,
                              hipStream_t stream) {
    const float* hidden = (const float*)d_in[0];
    const int*   mask   = (const int*)d_in[1];
    const float* Wqkv   = (const float*)d_in[2];
    const float* Wo     = (const float*)d_in[3];
    float* out = (float*)d_out;

    const int M = BATCH * SEQ;   // 8192

    // workspace carve (bytes), all 256B-aligned
    char* w = (char*)d_ws;
    __hip_bfloat16* qkv_bf  = (__hip_bfloat16*)(w);              // 8192x2304x2 = 37,748,736
    __hip_bfloat16* hid_bf  = (__hip_bfloat16*)(w + 37748736);   // 8192x768x2  = 12,582,912
    __hip_bfloat16* wqkv_bf = (__hip_bfloat16*)(w + 50331648);   // 2304x768x2  =  3,538,944
    __hip_bfloat16* wo_bf   = (__hip_bfloat16*)(w + 53870592);   //  768x768x2  =  1,179,648
    __hip_bfloat16* attn_bf = (__hip_bfloat16*)(w + 55050240);   // 8192x768x2  = 12,582,912
    // total 67,633,152 bytes

    // 0) casts to bf16
    cast_f32_bf16<<<(M * DMODEL / 4 + 255) / 256, 256, 0, stream>>>(hidden, hid_bf, M * DMODEL / 4);
    cast_f32_bf16<<<(QKV_LD * DMODEL / 4 + 255) / 256, 256, 0, stream>>>(Wqkv, wqkv_bf, QKV_LD * DMODEL / 4);
    cast_f32_bf16<<<(DMODEL * DMODEL / 4 + 255) / 256, 256, 0, stream>>>(Wo, wo_bf, DMODEL * DMODEL / 4);

    // 1) QKV projection (bf16 MFMA): qkv[m,e] = sum_d h[m,d]*Wqkv[e,d]
    {
        dim3 grid(QKV_LD / 128, M / 128);   // (18, 64)
        gemm_nt_bf16<__hip_bfloat16><<<grid, 256, 0, stream>>>(hid_bf, wqkv_bf, qkv_bf,
                                                               DMODEL, DMODEL, QKV_LD, DMODEL);
    }
    // 2) RoPE in place on q,k
    rope_kernel<<<M * NHEADS * 32 / 256, 256, 0, stream>>>(qkv_bf);

    // 3) sliding-window attention -> attn_bf
    {
        dim3 grid(SEQ / 16, NHEADS, BATCH); // (128, 12, 4)
        attn_kernel<<<grid, 256, 0, stream>>>(qkv_bf, mask, attn_bf);
    }
    // 4) output projection (bf16 MFMA, fp32 out): out[m,e] = sum_d attn[m,d]*Wo[e,d]
    {
        dim3 grid(DMODEL / 128, M / 128);   // (6, 64)
        gemm_nt_bf16<float><<<grid, 256, 0, stream>>>(attn_bf, wo_bf, out,
                                                      DMODEL, DMODEL, DMODEL, DMODEL);
    }
}

// Round 3
// 213.291 us; speedup vs baseline: 5.4719x; 1.2306x over previous
//
#include <hip/hip_runtime.h>
#include <hip/hip_bf16.h>
#include <math.h>

// Problem constants (ModernBERT attention)
#define BATCH 4
#define SEQ   2048
#define DMODEL 768
#define NHEADS 12
#define HDIM  64
#define WIN   64          // window each side
#define QKV_LD 2304       // 3*DMODEL

typedef __attribute__((ext_vector_type(8))) short bf16x8;  // 8 bf16 = 4 VGPRs
typedef __attribute__((ext_vector_type(4))) float f32x4;

typedef __attribute__((address_space(1))) const unsigned int guint;
typedef __attribute__((address_space(3))) unsigned int luint;

__device__ inline void gl_lds16(const __hip_bfloat16* g, __hip_bfloat16* l) {
    __builtin_amdgcn_global_load_lds((guint*)g, (luint*)l, 16, 0, 0);
}

__device__ inline void store_out(float* p, float v) { *p = v; }
__device__ inline void store_out(__hip_bfloat16* p, float v) { *p = __float2bfloat16(v); }

// ---------------------------------------------------------------------------
// cast fp32 -> bf16, 4 elems/thread
// ---------------------------------------------------------------------------
__global__ __launch_bounds__(256) void cast_f32_bf16(const float* __restrict__ in,
                                                     __hip_bfloat16* __restrict__ out, int n4) {
    int i = blockIdx.x * blockDim.x + threadIdx.x;
    if (i < n4) {
        float4 v = ((const float4*)in)[i];
        union { ushort4 u; __hip_bfloat16 h[4]; } o;
        o.h[0] = __float2bfloat16(v.x); o.h[1] = __float2bfloat16(v.y);
        o.h[2] = __float2bfloat16(v.z); o.h[3] = __float2bfloat16(v.w);
        ((ushort4*)out)[i] = o.u;
    }
}

// ---------------------------------------------------------------------------
// rope cos/sin table: tab[t*32+j] = (cos(t*invf_j), sin(t*invf_j))
// ---------------------------------------------------------------------------
__global__ __launch_bounds__(256) void rope_table(float2* __restrict__ tab) {
    int idx = blockIdx.x * 256 + threadIdx.x;   // SEQ*32 = 65536
    int t = idx >> 5, j = idx & 31;
    const float L2T_OVER_32 = 13.287712379549449f / 32.0f;  // log2(10000)/32
    float inv = exp2f(-(float)j * L2T_OVER_32);
    float s, c;
    sincosf((float)t * inv, &s, &c);
    tab[idx] = make_float2(c, s);
}

// ---------------------------------------------------------------------------
// bf16 MFMA NT GEMM: C[m,n] = sum_k A[m*lda+k]*B[n*ldb+k]
// BM=BN=128, BK=32, 4 waves x (4x4) 16x16x32 frags. global_load_lds staging.
// Optional fused RoPE epilogue (rope_tab != nullptr): rotate column pairs
// (j, j+32) within each 64-col head for columns < 1536 (q,k regions).
// ---------------------------------------------------------------------------
template <typename OutT>
__global__ __launch_bounds__(256) void gemm_nt_bf16(const __hip_bfloat16* __restrict__ A,
                                                    const __hip_bfloat16* __restrict__ B,
                                                    OutT* __restrict__ C,
                                                    int lda, int ldb, int ldc, int K,
                                                    const float2* __restrict__ rope_tab) {
    __shared__ __align__(16) __hip_bfloat16 As[128 * 32];
    __shared__ __align__(16) __hip_bfloat16 Bs[128 * 32];

    const int tid  = threadIdx.x;
    const int lane = tid & 63;
    const int wave = tid >> 6;
    const int wr   = wave >> 1;
    const int wc   = wave & 1;
    const int fr   = lane & 15;
    const int quad = lane >> 4;
    const int m0   = blockIdx.y * 128;
    const int n0   = blockIdx.x * 128;

    f32x4 acc[4][4];
#pragma unroll
    for (int i = 0; i < 4; i++)
#pragma unroll
        for (int j = 0; j < 4; j++) acc[i][j] = (f32x4){0.f, 0.f, 0.f, 0.f};

    for (int k0 = 0; k0 < K; k0 += 32) {
        __syncthreads();
#pragma unroll
        for (int c = 0; c < 2; c++) {
            int e = (wave * 2 + c) * 512 + lane * 8;
            int row = e >> 5, col = e & 31;
            gl_lds16(A + (size_t)(m0 + row) * lda + k0 + col, As + e);
            gl_lds16(B + (size_t)(n0 + row) * ldb + k0 + col, Bs + e);
        }
        __syncthreads();

        bf16x8 af[4], bf_[4];
#pragma unroll
        for (int mi = 0; mi < 4; mi++)
            af[mi] = *(const bf16x8*)(As + (wr * 64 + mi * 16 + fr) * 32 + quad * 8);
#pragma unroll
        for (int ni = 0; ni < 4; ni++)
            bf_[ni] = *(const bf16x8*)(Bs + (wc * 64 + ni * 16 + fr) * 32 + quad * 8);
#pragma unroll
        for (int mi = 0; mi < 4; mi++)
#pragma unroll
            for (int ni = 0; ni < 4; ni++)
                acc[mi][ni] = __builtin_amdgcn_mfma_f32_16x16x32_bf16(af[mi], bf_[ni], acc[mi][ni], 0, 0, 0);
    }

    // fused RoPE: 64-col group b0 covers exactly one head; pairs (ni, ni+2)
    const int b0 = n0 + wc * 64;
    if (rope_tab != nullptr && b0 < 2 * DMODEL) {
#pragma unroll
        for (int mi = 0; mi < 4; mi++) {
#pragma unroll
            for (int r = 0; r < 4; r++) {
                int t = (m0 + wr * 64 + mi * 16 + quad * 4 + r) & (SEQ - 1);
#pragma unroll
                for (int ni = 0; ni < 2; ni++) {
                    float2 cs = rope_tab[t * 32 + ni * 16 + fr];
                    float x0 = acc[mi][ni][r], x1 = acc[mi][ni + 2][r];
                    acc[mi][ni][r]     = x0 * cs.x - x1 * cs.y;
                    acc[mi][ni + 2][r] = x0 * cs.y + x1 * cs.x;
                }
            }
        }
    }

#pragma unroll
    for (int mi = 0; mi < 4; mi++)
#pragma unroll
        for (int ni = 0; ni < 4; ni++) {
            f32x4 v = acc[mi][ni];
            int gc = b0 + ni * 16 + fr;
            size_t rbase = (size_t)(m0 + wr * 64 + mi * 16 + quad * 4);
#pragma unroll
            for (int r = 0; r < 4; r++)
                store_out(&C[(rbase + r) * ldc + gc], v[r]);
        }
}

// ---------------------------------------------------------------------------
// Sliding-window attention, one block per (b, head, 64-query tile).
// QK^T and PV both via MFMA; in-register softmax via quad-group shuffles.
// LDS (60 KB): Ks[192][72] (aliased by P[64][192] after QK^T), Qs[64][72],
// Vt[64][192] (V transposed, XOR-swizzled 8-elem chunks).
// ---------------------------------------------------------------------------
#define KSLD 72
#define PLD  192

__global__ __launch_bounds__(256) void attn_kernel(const __hip_bfloat16* __restrict__ qkv,
                                                   const int* __restrict__ mask,
                                                   __hip_bfloat16* __restrict__ attn) {
    __shared__ __align__(16) char smem[61440];
    __hip_bfloat16* Ks = (__hip_bfloat16*)smem;            // [192][72]
    __hip_bfloat16* Pb = (__hip_bfloat16*)smem;            // [64][192] swizzled (aliases Ks)
    __hip_bfloat16* Qs = (__hip_bfloat16*)(smem + 27648);  // [64][72]
    __hip_bfloat16* Vt = (__hip_bfloat16*)(smem + 36864);  // [64][192] swizzled

    const int tid  = threadIdx.x;
    const int lane = tid & 63;
    const int wave = tid >> 6;
    const int fr   = lane & 15;
    const int quad = lane >> 4;

    const int q0  = blockIdx.x * 64;
    const int head = blockIdx.y;
    const int b   = blockIdx.z;
    const int klo = max(0, q0 - WIN);
    const int khi = min(SEQ, q0 + 64 + WIN);
    const int nk  = khi - klo;     // 128 or 192
    const int nt  = nk >> 4;       // 8 or 12
    const int nkc = nk >> 5;       // 4 or 6

    const size_t rowbase = (size_t)(b * SEQ) * QKV_LD + head * HDIM;

    // ---- stage Q [64][72]: 512 uint4 tasks
#pragma unroll
    for (int it = 0; it < 2; it++) {
        int task = tid + it * 256;
        int row = task >> 3, g = task & 7;
        uint4 v = *(const uint4*)(qkv + rowbase + (size_t)(q0 + row) * QKV_LD + g * 8);
        *(uint4*)(Qs + row * KSLD + g * 8) = v;
    }
    // ---- stage K [nk][72]: up to 1536 uint4 tasks
    for (int task = tid; task < nk * 8; task += 256) {
        int row = task >> 3, g = task & 7;
        uint4 v = *(const uint4*)(qkv + rowbase + (size_t)(klo + row) * QKV_LD + DMODEL + g * 8);
        *(uint4*)(Ks + row * KSLD + g * 8) = v;
    }
    // ---- stage V transposed [64][nk], XOR-swizzled chunks of 8
    {
        int h = lane;
        const __hip_bfloat16* vb = qkv + rowbase + 2 * DMODEL + h;
        int ng = nk >> 3;
        for (int g = wave; g < ng; g += 4) {
            unsigned int u0, u1, u2, u3;
            {
                unsigned short a0 = *(const unsigned short*)(vb + (size_t)(klo + g * 8 + 0) * QKV_LD);
                unsigned short a1 = *(const unsigned short*)(vb + (size_t)(klo + g * 8 + 1) * QKV_LD);
                unsigned short a2 = *(const unsigned short*)(vb + (size_t)(klo + g * 8 + 2) * QKV_LD);
                unsigned short a3 = *(const unsigned short*)(vb + (size_t)(klo + g * 8 + 3) * QKV_LD);
                unsigned short a4 = *(const unsigned short*)(vb + (size_t)(klo + g * 8 + 4) * QKV_LD);
                unsigned short a5 = *(const unsigned short*)(vb + (size_t)(klo + g * 8 + 5) * QKV_LD);
                unsigned short a6 = *(const unsigned short*)(vb + (size_t)(klo + g * 8 + 6) * QKV_LD);
                unsigned short a7 = *(const unsigned short*)(vb + (size_t)(klo + g * 8 + 7) * QKV_LD);
                u0 = (unsigned int)a0 | ((unsigned int)a1 << 16);
                u1 = (unsigned int)a2 | ((unsigned int)a3 << 16);
                u2 = (unsigned int)a4 | ((unsigned int)a5 << 16);
                u3 = (unsigned int)a6 | ((unsigned int)a7 << 16);
            }
            int cs = g ^ (h & 7);
            *(uint4*)(Vt + h * PLD + cs * 8) = make_uint4(u0, u1, u2, u3);
        }
    }
    __syncthreads();

    // ---- QK^T via MFMA; wave owns 16 query rows
    const int qrow0 = q0 + wave * 16;
    bf16x8 aq0 = *(const bf16x8*)(Qs + (wave * 16 + fr) * KSLD + quad * 8);
    bf16x8 aq1 = *(const bf16x8*)(Qs + (wave * 16 + fr) * KSLD + 32 + quad * 8);

    const int* mb = mask + b * SEQ;
    int mq[4];
#pragma unroll
    for (int r = 0; r < 4; r++) mq[r] = mb[qrow0 + quad * 4 + r];

    f32x4 sc[12];
#pragma unroll
    for (int kt = 0; kt < 12; kt++) sc[kt] = (f32x4){-1e30f, -1e30f, -1e30f, -1e30f};

#pragma unroll
    for (int kt = 0; kt < 12; kt++) {
        if (kt < nt) {
            int kg = klo + kt * 16 + fr;
            bf16x8 b0 = *(const bf16x8*)(Ks + (kt * 16 + fr) * KSLD + quad * 8);
            bf16x8 b1 = *(const bf16x8*)(Ks + (kt * 16 + fr) * KSLD + 32 + quad * 8);
            f32x4 a = (f32x4){0.f, 0.f, 0.f, 0.f};
            a = __builtin_amdgcn_mfma_f32_16x16x32_bf16(aq0, b0, a, 0, 0, 0);
            a = __builtin_amdgcn_mfma_f32_16x16x32_bf16(aq1, b1, a, 0, 0, 0);
            int mk = mb[kg];
            f32x4 s;
#pragma unroll
            for (int r = 0; r < 4; r++) {
                int qg = qrow0 + quad * 4 + r;
                bool ok = (abs(qg - kg) <= WIN) && (mk != 0) && (mq[r] != 0);
                s[r] = ok ? a[r] * 0.125f : -1e30f;
            }
            sc[kt] = s;
        }
    }

    // ---- in-register softmax: reduce across fr lanes (same quad group)
    f32x4 mx = sc[0];
#pragma unroll
    for (int kt = 1; kt < 12; kt++)
#pragma unroll
        for (int r = 0; r < 4; r++) mx[r] = fmaxf(mx[r], sc[kt][r]);
#pragma unroll
    for (int off = 8; off >= 1; off >>= 1)
#pragma unroll
        for (int r = 0; r < 4; r++) mx[r] = fmaxf(mx[r], __shfl_xor(mx[r], off));

    f32x4 sum = (f32x4){0.f, 0.f, 0.f, 0.f};
#pragma unroll
    for (int kt = 0; kt < 12; kt++)
#pragma unroll
        for (int r = 0; r < 4; r++) {
            float e = __expf(sc[kt][r] - mx[r]);
            sc[kt][r] = e;
            sum[r] += e;
        }
#pragma unroll
    for (int off = 8; off >= 1; off >>= 1)
#pragma unroll
        for (int r = 0; r < 4; r++) sum[r] += __shfl_xor(sum[r], off);
    f32x4 rs;
#pragma unroll
    for (int r = 0; r < 4; r++) rs[r] = 1.0f / sum[r];

    // ---- write P (bf16, A-layout-friendly, swizzled) into Ks space
    __syncthreads();   // all waves done reading Ks/Qs
#pragma unroll
    for (int kt = 0; kt < 12; kt++) {
        if (kt < nt) {
#pragma unroll
            for (int r = 0; r < 4; r++) {
                int prow = wave * 16 + quad * 4 + r;
                int c = kt * 2 + (fr >> 3);
                int cs = c ^ (prow & 7);
                Pb[prow * PLD + cs * 8 + (fr & 7)] = __float2bfloat16(sc[kt][r] * rs[r]);
            }
        }
    }
    __syncthreads();

    // ---- PV via MFMA: O[16q][64h] per wave
    f32x4 o[4];
#pragma unroll
    for (int ht = 0; ht < 4; ht++) o[ht] = (f32x4){0.f, 0.f, 0.f, 0.f};

#pragma unroll
    for (int kc = 0; kc < 6; kc++) {
        if (kc < nkc) {
            int cs = (kc * 4 + quad) ^ (fr & 7);
            bf16x8 ap = *(const bf16x8*)(Pb + (wave * 16 + fr) * PLD + cs * 8);
#pragma unroll
            for (int ht = 0; ht < 4; ht++) {
                bf16x8 bv = *(const bf16x8*)(Vt + (ht * 16 + fr) * PLD + cs * 8);
                o[ht] = __builtin_amdgcn_mfma_f32_16x16x32_bf16(ap, bv, o[ht], 0, 0, 0);
            }
        }
    }

    // ---- store O (bf16) to attn [B*T, 768]
    __hip_bfloat16* ob = attn + (size_t)(b * SEQ + qrow0) * DMODEL + head * HDIM;
#pragma unroll
    for (int r = 0; r < 4; r++)
#pragma unroll
        for (int ht = 0; ht < 4; ht++)
            ob[(size_t)(quad * 4 + r) * DMODEL + ht * 16 + fr] = __float2bfloat16(o[ht][r]);
}

// ---------------------------------------------------------------------------
extern "C" void kernel_launch(void* const* d_in, const int* in_sizes, int n_in,
                              void* d_out, int out_size, void* d_ws, size_t ws_size,
                              hipStream_t stream) {
    const float* hidden = (const float*)d_in[0];
    const int*   mask   = (const int*)d_in[1];
    const float* Wqkv   = (const float*)d_in[2];
    const float* Wo     = (const float*)d_in[3];
    float* out = (float*)d_out;

    const int M = BATCH * SEQ;   // 8192

    char* w = (char*)d_ws;
    __hip_bfloat16* qkv_bf  = (__hip_bfloat16*)(w);              // 37,748,736
    __hip_bfloat16* hid_bf  = (__hip_bfloat16*)(w + 37748736);   // 12,582,912
    __hip_bfloat16* wqkv_bf = (__hip_bfloat16*)(w + 50331648);   //  3,538,944
    __hip_bfloat16* wo_bf   = (__hip_bfloat16*)(w + 53870592);   //  1,179,648
    __hip_bfloat16* attn_bf = (__hip_bfloat16*)(w + 55050240);   // 12,582,912
    float2*         tab     = (float2*)(w + 67633152);           //    524,288

    // 0) casts + rope table
    cast_f32_bf16<<<(M * DMODEL / 4 + 255) / 256, 256, 0, stream>>>(hidden, hid_bf, M * DMODEL / 4);
    cast_f32_bf16<<<(QKV_LD * DMODEL / 4 + 255) / 256, 256, 0, stream>>>(Wqkv, wqkv_bf, QKV_LD * DMODEL / 4);
    cast_f32_bf16<<<(DMODEL * DMODEL / 4 + 255) / 256, 256, 0, stream>>>(Wo, wo_bf, DMODEL * DMODEL / 4);
    rope_table<<<SEQ * 32 / 256, 256, 0, stream>>>(tab);

    // 1) QKV projection + fused RoPE
    {
        dim3 grid(QKV_LD / 128, M / 128);   // (18, 64)
        gemm_nt_bf16<__hip_bfloat16><<<grid, 256, 0, stream>>>(hid_bf, wqkv_bf, qkv_bf,
                                                               DMODEL, DMODEL, QKV_LD, DMODEL, tab);
    }
    // 2) sliding-window attention (MFMA QK^T + MFMA PV)
    {
        dim3 grid(SEQ / 64, NHEADS, BATCH); // (32, 12, 4)
        attn_kernel<<<grid, 256, 0, stream>>>(qkv_bf, mask, attn_bf);
    }
    // 3) output projection
    {
        dim3 grid(DMODEL / 128, M / 128);   // (6, 64)
        gemm_nt_bf16<float><<<grid, 256, 0, stream>>>(attn_bf, wo_bf, out,
                                                      DMODEL, DMODEL, DMODEL, DMODEL, nullptr);
    }
}

// Round 4
// 194.023 us; speedup vs baseline: 6.0153x; 1.0993x over previous
//
#include <hip/hip_runtime.h>
#include <hip/hip_bf16.h>
#include <math.h>

// Problem constants (ModernBERT attention)
#define BATCH 4
#define SEQ   2048
#define DMODEL 768
#define NHEADS 12
#define HDIM  64
#define WIN   64          // window each side
#define QKV_LD 2304       // 3*DMODEL

typedef __attribute__((ext_vector_type(8))) short bf16x8;  // 8 bf16 = 4 VGPRs
typedef __attribute__((ext_vector_type(4))) float f32x4;

typedef __attribute__((address_space(1))) const unsigned int guint;
typedef __attribute__((address_space(3))) unsigned int luint;

__device__ inline void gl_lds16(const __hip_bfloat16* g, __hip_bfloat16* l) {
    __builtin_amdgcn_global_load_lds((guint*)g, (luint*)l, 16, 0, 0);
}

__device__ inline void store_out(float* p, float v) { *p = v; }
__device__ inline void store_out(__hip_bfloat16* p, float v) { *p = __float2bfloat16(v); }

// ---------------------------------------------------------------------------
// fused setup: cast hidden/Wqkv/Wo to bf16 + build rope cos/sin table.
// One launch instead of four; all jobs are independent elementwise ranges.
// ---------------------------------------------------------------------------
#define N4_HID  (BATCH * SEQ * DMODEL / 4)     // 1,572,864
#define N4_WQKV (QKV_LD * DMODEL / 4)          //   442,368
#define N4_WO   (DMODEL * DMODEL / 4)          //   147,456
#define N_ROPE  (SEQ * 32)                     //    65,536
#define SETUP_TOTAL (N4_HID + N4_WQKV + N4_WO + N_ROPE)

__device__ inline void cast4(const float* in, __hip_bfloat16* out, int i) {
    float4 v = ((const float4*)in)[i];
    union { ushort4 u; __hip_bfloat16 h[4]; } o;
    o.h[0] = __float2bfloat16(v.x); o.h[1] = __float2bfloat16(v.y);
    o.h[2] = __float2bfloat16(v.z); o.h[3] = __float2bfloat16(v.w);
    ((ushort4*)out)[i] = o.u;
}

__global__ __launch_bounds__(256) void setup_kernel(const float* __restrict__ hidden,
                                                    const float* __restrict__ Wqkv,
                                                    const float* __restrict__ Wo,
                                                    __hip_bfloat16* __restrict__ hid_bf,
                                                    __hip_bfloat16* __restrict__ wqkv_bf,
                                                    __hip_bfloat16* __restrict__ wo_bf,
                                                    float2* __restrict__ tab) {
    int id = blockIdx.x * 256 + threadIdx.x;
    if (id < N4_HID) {
        cast4(hidden, hid_bf, id);
    } else if (id < N4_HID + N4_WQKV) {
        cast4(Wqkv, wqkv_bf, id - N4_HID);
    } else if (id < N4_HID + N4_WQKV + N4_WO) {
        cast4(Wo, wo_bf, id - N4_HID - N4_WQKV);
    } else if (id < SETUP_TOTAL) {
        int idx = id - (N4_HID + N4_WQKV + N4_WO);
        int t = idx >> 5, j = idx & 31;
        const float L2T_OVER_32 = 13.287712379549449f / 32.0f;  // log2(10000)/32
        float inv = exp2f(-(float)j * L2T_OVER_32);
        float s, c;
        sincosf((float)t * inv, &s, &c);
        tab[idx] = make_float2(c, s);
    }
}

// ---------------------------------------------------------------------------
// bf16 MFMA NT GEMM: C[m,n] = sum_k A[m*lda+k]*B[n*ldb+k]
// BM=BN=128, BK=32, 4 waves x (4x4) 16x16x32 frags, global_load_lds staging.
// 1D grid with XCD-aware swizzle: XCD (bid&7) owns m-tiles [8x, 8x+8) for all
// n-tiles -> per-XCD working set (1.5 MB A-panel + B) is L2-resident.
// Requires gridM == 64 m-tiles (M=8192). Optional fused RoPE epilogue.
// ---------------------------------------------------------------------------
template <typename OutT>
__global__ __launch_bounds__(256) void gemm_nt_bf16(const __hip_bfloat16* __restrict__ A,
                                                    const __hip_bfloat16* __restrict__ B,
                                                    OutT* __restrict__ C,
                                                    int lda, int ldb, int ldc, int K,
                                                    const float2* __restrict__ rope_tab) {
    __shared__ __align__(16) __hip_bfloat16 As[128 * 32];
    __shared__ __align__(16) __hip_bfloat16 Bs[128 * 32];

    const int tid  = threadIdx.x;
    const int lane = tid & 63;
    const int wave = tid >> 6;
    const int wr   = wave >> 1;
    const int wc   = wave & 1;
    const int fr   = lane & 15;
    const int quad = lane >> 4;

    // XCD-aware swizzle (gridM = 64 m-tiles, 8 per XCD)
    const int bid = blockIdx.x;
    const int x   = bid & 7;
    const int j   = bid >> 3;
    const int m0  = (x * 8 + (j & 7)) * 128;
    const int n0  = (j >> 3) * 128;

    f32x4 acc[4][4];
#pragma unroll
    for (int i = 0; i < 4; i++)
#pragma unroll
        for (int jj = 0; jj < 4; jj++) acc[i][jj] = (f32x4){0.f, 0.f, 0.f, 0.f};

    for (int k0 = 0; k0 < K; k0 += 32) {
        __syncthreads();
#pragma unroll
        for (int c = 0; c < 2; c++) {
            int e = (wave * 2 + c) * 512 + lane * 8;
            int row = e >> 5, col = e & 31;
            gl_lds16(A + (size_t)(m0 + row) * lda + k0 + col, As + e);
            gl_lds16(B + (size_t)(n0 + row) * ldb + k0 + col, Bs + e);
        }
        __syncthreads();

        bf16x8 af[4], bf_[4];
#pragma unroll
        for (int mi = 0; mi < 4; mi++)
            af[mi] = *(const bf16x8*)(As + (wr * 64 + mi * 16 + fr) * 32 + quad * 8);
#pragma unroll
        for (int ni = 0; ni < 4; ni++)
            bf_[ni] = *(const bf16x8*)(Bs + (wc * 64 + ni * 16 + fr) * 32 + quad * 8);
#pragma unroll
        for (int mi = 0; mi < 4; mi++)
#pragma unroll
            for (int ni = 0; ni < 4; ni++)
                acc[mi][ni] = __builtin_amdgcn_mfma_f32_16x16x32_bf16(af[mi], bf_[ni], acc[mi][ni], 0, 0, 0);
    }

    // fused RoPE: 64-col group b0 covers exactly one head; pairs (ni, ni+2)
    const int b0 = n0 + wc * 64;
    if (rope_tab != nullptr && b0 < 2 * DMODEL) {
#pragma unroll
        for (int mi = 0; mi < 4; mi++) {
#pragma unroll
            for (int r = 0; r < 4; r++) {
                int t = (m0 + wr * 64 + mi * 16 + quad * 4 + r) & (SEQ - 1);
#pragma unroll
                for (int ni = 0; ni < 2; ni++) {
                    float2 cs = rope_tab[t * 32 + ni * 16 + fr];
                    float x0 = acc[mi][ni][r], x1 = acc[mi][ni + 2][r];
                    acc[mi][ni][r]     = x0 * cs.x - x1 * cs.y;
                    acc[mi][ni + 2][r] = x0 * cs.y + x1 * cs.x;
                }
            }
        }
    }

#pragma unroll
    for (int mi = 0; mi < 4; mi++)
#pragma unroll
        for (int ni = 0; ni < 4; ni++) {
            f32x4 v = acc[mi][ni];
            int gc = b0 + ni * 16 + fr;
            size_t rbase = (size_t)(m0 + wr * 64 + mi * 16 + quad * 4);
#pragma unroll
            for (int r = 0; r < 4; r++)
                store_out(&C[(rbase + r) * ldc + gc], v[r]);
        }
}

// ---------------------------------------------------------------------------
// Sliding-window attention, one block per (b, head, 64-query tile).
// QK^T and PV both via MFMA; in-register softmax via quad-group shuffles.
// 1D grid, XCD-aware: XCD (bid&7) owns (batch = x>>1, 16 contiguous q-tiles)
// for all heads -> per-XCD K/V span ~5 MB, mostly L2-resident.
// LDS (60 KB): Ks[192][72] (aliased by P[64][192] after QK^T), Qs[64][72],
// Vt[64][192] (V transposed, XOR-swizzled 8-elem chunks).
// ---------------------------------------------------------------------------
#define KSLD 72
#define PLD  192

__global__ __launch_bounds__(256) void attn_kernel(const __hip_bfloat16* __restrict__ qkv,
                                                   const int* __restrict__ mask,
                                                   __hip_bfloat16* __restrict__ attn) {
    __shared__ __align__(16) char smem[61440];
    __hip_bfloat16* Ks = (__hip_bfloat16*)smem;            // [192][72]
    __hip_bfloat16* Pb = (__hip_bfloat16*)smem;            // [64][192] swizzled (aliases Ks)
    __hip_bfloat16* Qs = (__hip_bfloat16*)(smem + 27648);  // [64][72]
    __hip_bfloat16* Vt = (__hip_bfloat16*)(smem + 36864);  // [64][192] swizzled

    const int tid  = threadIdx.x;
    const int lane = tid & 63;
    const int wave = tid >> 6;
    const int fr   = lane & 15;
    const int quad = lane >> 4;

    // XCD-aware swizzle: 1536 blocks = 8 XCDs x 192
    const int bid  = blockIdx.x;
    const int x    = bid & 7;
    const int j    = bid >> 3;                 // 0..191
    const int b    = x >> 1;
    const int q0   = ((x & 1) * 16 + (j & 15)) * 64;
    const int head = j >> 4;                   // 0..11

    const int klo = max(0, q0 - WIN);
    const int khi = min(SEQ, q0 + 64 + WIN);
    const int nk  = khi - klo;     // 128 or 192
    const int nt  = nk >> 4;       // 8 or 12
    const int nkc = nk >> 5;       // 4 or 6

    const size_t rowbase = (size_t)(b * SEQ) * QKV_LD + head * HDIM;

    // ---- stage Q [64][72]: 512 uint4 tasks
#pragma unroll
    for (int it = 0; it < 2; it++) {
        int task = tid + it * 256;
        int row = task >> 3, g = task & 7;
        uint4 v = *(const uint4*)(qkv + rowbase + (size_t)(q0 + row) * QKV_LD + g * 8);
        *(uint4*)(Qs + row * KSLD + g * 8) = v;
    }
    // ---- stage K [nk][72]: up to 1536 uint4 tasks
    for (int task = tid; task < nk * 8; task += 256) {
        int row = task >> 3, g = task & 7;
        uint4 v = *(const uint4*)(qkv + rowbase + (size_t)(klo + row) * QKV_LD + DMODEL + g * 8);
        *(uint4*)(Ks + row * KSLD + g * 8) = v;
    }
    // ---- stage V transposed [64][nk], XOR-swizzled chunks of 8
    {
        int h = lane;
        const __hip_bfloat16* vb = qkv + rowbase + 2 * DMODEL + h;
        int ng = nk >> 3;
        for (int g = wave; g < ng; g += 4) {
            unsigned int u0, u1, u2, u3;
            {
                unsigned short a0 = *(const unsigned short*)(vb + (size_t)(klo + g * 8 + 0) * QKV_LD);
                unsigned short a1 = *(const unsigned short*)(vb + (size_t)(klo + g * 8 + 1) * QKV_LD);
                unsigned short a2 = *(const unsigned short*)(vb + (size_t)(klo + g * 8 + 2) * QKV_LD);
                unsigned short a3 = *(const unsigned short*)(vb + (size_t)(klo + g * 8 + 3) * QKV_LD);
                unsigned short a4 = *(const unsigned short*)(vb + (size_t)(klo + g * 8 + 4) * QKV_LD);
                unsigned short a5 = *(const unsigned short*)(vb + (size_t)(klo + g * 8 + 5) * QKV_LD);
                unsigned short a6 = *(const unsigned short*)(vb + (size_t)(klo + g * 8 + 6) * QKV_LD);
                unsigned short a7 = *(const unsigned short*)(vb + (size_t)(klo + g * 8 + 7) * QKV_LD);
                u0 = (unsigned int)a0 | ((unsigned int)a1 << 16);
                u1 = (unsigned int)a2 | ((unsigned int)a3 << 16);
                u2 = (unsigned int)a4 | ((unsigned int)a5 << 16);
                u3 = (unsigned int)a6 | ((unsigned int)a7 << 16);
            }
            int cs = g ^ (h & 7);
            *(uint4*)(Vt + h * PLD + cs * 8) = make_uint4(u0, u1, u2, u3);
        }
    }
    __syncthreads();

    // ---- QK^T via MFMA; wave owns 16 query rows
    const int qrow0 = q0 + wave * 16;
    bf16x8 aq0 = *(const bf16x8*)(Qs + (wave * 16 + fr) * KSLD + quad * 8);
    bf16x8 aq1 = *(const bf16x8*)(Qs + (wave * 16 + fr) * KSLD + 32 + quad * 8);

    const int* mb = mask + b * SEQ;
    int mq[4];
#pragma unroll
    for (int r = 0; r < 4; r++) mq[r] = mb[qrow0 + quad * 4 + r];

    f32x4 sc[12];
#pragma unroll
    for (int kt = 0; kt < 12; kt++) sc[kt] = (f32x4){-1e30f, -1e30f, -1e30f, -1e30f};

#pragma unroll
    for (int kt = 0; kt < 12; kt++) {
        if (kt < nt) {
            int kg = klo + kt * 16 + fr;
            bf16x8 b0 = *(const bf16x8*)(Ks + (kt * 16 + fr) * KSLD + quad * 8);
            bf16x8 b1 = *(const bf16x8*)(Ks + (kt * 16 + fr) * KSLD + 32 + quad * 8);
            f32x4 a = (f32x4){0.f, 0.f, 0.f, 0.f};
            a = __builtin_amdgcn_mfma_f32_16x16x32_bf16(aq0, b0, a, 0, 0, 0);
            a = __builtin_amdgcn_mfma_f32_16x16x32_bf16(aq1, b1, a, 0, 0, 0);
            int mk = mb[kg];
            f32x4 s;
#pragma unroll
            for (int r = 0; r < 4; r++) {
                int qg = qrow0 + quad * 4 + r;
                bool ok = (abs(qg - kg) <= WIN) && (mk != 0) && (mq[r] != 0);
                s[r] = ok ? a[r] * 0.125f : -1e30f;
            }
            sc[kt] = s;
        }
    }

    // ---- in-register softmax: reduce across fr lanes (same quad group)
    f32x4 mx = sc[0];
#pragma unroll
    for (int kt = 1; kt < 12; kt++)
#pragma unroll
        for (int r = 0; r < 4; r++) mx[r] = fmaxf(mx[r], sc[kt][r]);
#pragma unroll
    for (int off = 8; off >= 1; off >>= 1)
#pragma unroll
        for (int r = 0; r < 4; r++) mx[r] = fmaxf(mx[r], __shfl_xor(mx[r], off));

    f32x4 sum = (f32x4){0.f, 0.f, 0.f, 0.f};
#pragma unroll
    for (int kt = 0; kt < 12; kt++)
#pragma unroll
        for (int r = 0; r < 4; r++) {
            float e = __expf(sc[kt][r] - mx[r]);
            sc[kt][r] = e;
            sum[r] += e;
        }
#pragma unroll
    for (int off = 8; off >= 1; off >>= 1)
#pragma unroll
        for (int r = 0; r < 4; r++) sum[r] += __shfl_xor(sum[r], off);
    f32x4 rs;
#pragma unroll
    for (int r = 0; r < 4; r++) rs[r] = 1.0f / sum[r];

    // ---- write P (bf16, A-layout-friendly, swizzled) into Ks space
    __syncthreads();   // all waves done reading Ks/Qs
#pragma unroll
    for (int kt = 0; kt < 12; kt++) {
        if (kt < nt) {
#pragma unroll
            for (int r = 0; r < 4; r++) {
                int prow = wave * 16 + quad * 4 + r;
                int c = kt * 2 + (fr >> 3);
                int cs = c ^ (prow & 7);
                Pb[prow * PLD + cs * 8 + (fr & 7)] = __float2bfloat16(sc[kt][r] * rs[r]);
            }
        }
    }
    __syncthreads();

    // ---- PV via MFMA: O[16q][64h] per wave
    f32x4 o[4];
#pragma unroll
    for (int ht = 0; ht < 4; ht++) o[ht] = (f32x4){0.f, 0.f, 0.f, 0.f};

#pragma unroll
    for (int kc = 0; kc < 6; kc++) {
        if (kc < nkc) {
            int cs = (kc * 4 + quad) ^ (fr & 7);
            bf16x8 ap = *(const bf16x8*)(Pb + (wave * 16 + fr) * PLD + cs * 8);
#pragma unroll
            for (int ht = 0; ht < 4; ht++) {
                bf16x8 bv = *(const bf16x8*)(Vt + (ht * 16 + fr) * PLD + cs * 8);
                o[ht] = __builtin_amdgcn_mfma_f32_16x16x32_bf16(ap, bv, o[ht], 0, 0, 0);
            }
        }
    }

    // ---- store O (bf16) to attn [B*T, 768]
    __hip_bfloat16* ob = attn + (size_t)(b * SEQ + qrow0) * DMODEL + head * HDIM;
#pragma unroll
    for (int r = 0; r < 4; r++)
#pragma unroll
        for (int ht = 0; ht < 4; ht++)
            ob[(size_t)(quad * 4 + r) * DMODEL + ht * 16 + fr] = __float2bfloat16(o[ht][r]);
}

// ---------------------------------------------------------------------------
extern "C" void kernel_launch(void* const* d_in, const int* in_sizes, int n_in,
                              void* d_out, int out_size, void* d_ws, size_t ws_size,
                              hipStream_t stream) {
    const float* hidden = (const float*)d_in[0];
    const int*   mask   = (const int*)d_in[1];
    const float* Wqkv   = (const float*)d_in[2];
    const float* Wo     = (const float*)d_in[3];
    float* out = (float*)d_out;

    char* w = (char*)d_ws;
    __hip_bfloat16* qkv_bf  = (__hip_bfloat16*)(w);              // 37,748,736
    __hip_bfloat16* hid_bf  = (__hip_bfloat16*)(w + 37748736);   // 12,582,912
    __hip_bfloat16* wqkv_bf = (__hip_bfloat16*)(w + 50331648);   //  3,538,944
    __hip_bfloat16* wo_bf   = (__hip_bfloat16*)(w + 53870592);   //  1,179,648
    __hip_bfloat16* attn_bf = (__hip_bfloat16*)(w + 55050240);   // 12,582,912
    float2*         tab     = (float2*)(w + 67633152);           //    524,288

    // 0) fused setup: casts + rope table (one launch)
    setup_kernel<<<SETUP_TOTAL / 256, 256, 0, stream>>>(hidden, Wqkv, Wo,
                                                        hid_bf, wqkv_bf, wo_bf, tab);

    // 1) QKV projection + fused RoPE (XCD-swizzled 1D grid: 18 n-tiles x 64 m-tiles)
    gemm_nt_bf16<__hip_bfloat16><<<18 * 64, 256, 0, stream>>>(hid_bf, wqkv_bf, qkv_bf,
                                                              DMODEL, DMODEL, QKV_LD, DMODEL, tab);

    // 2) sliding-window attention (XCD-swizzled 1D grid)
    attn_kernel<<<(SEQ / 64) * NHEADS * BATCH, 256, 0, stream>>>(qkv_bf, mask, attn_bf);

    // 3) output projection (6 n-tiles x 64 m-tiles)
    gemm_nt_bf16<float><<<6 * 64, 256, 0, stream>>>(attn_bf, wo_bf, out,
                                                    DMODEL, DMODEL, DMODEL, DMODEL, nullptr);
}

// Round 5
// 192.135 us; speedup vs baseline: 6.0744x; 1.0098x over previous
//
#include <hip/hip_runtime.h>
#include <hip/hip_bf16.h>
#include <math.h>

// Problem constants (ModernBERT attention)
#define BATCH 4
#define SEQ   2048
#define DMODEL 768
#define NHEADS 12
#define HDIM  64
#define WIN   64          // window each side
#define QKV_LD 2304       // 3*DMODEL

typedef __attribute__((ext_vector_type(8))) short bf16x8;  // 8 bf16 = 4 VGPRs
typedef __attribute__((ext_vector_type(4))) float f32x4;

typedef __attribute__((address_space(1))) const unsigned int guint;
typedef __attribute__((address_space(3))) unsigned int luint;

__device__ inline void gl_lds16(const __hip_bfloat16* g, __hip_bfloat16* l) {
    __builtin_amdgcn_global_load_lds((guint*)g, (luint*)l, 16, 0, 0);
}

__device__ inline void to_out(float* p, float v) { *p = v; }
__device__ inline void to_out(__hip_bfloat16* p, float v) { *p = __float2bfloat16(v); }

// ---------------------------------------------------------------------------
// fused setup: cast hidden/Wqkv/Wo to bf16 + build rope cos/sin table.
// ---------------------------------------------------------------------------
#define N4_HID  (BATCH * SEQ * DMODEL / 4)     // 1,572,864
#define N4_WQKV (QKV_LD * DMODEL / 4)          //   442,368
#define N4_WO   (DMODEL * DMODEL / 4)          //   147,456
#define N_ROPE  (SEQ * 32)                     //    65,536
#define SETUP_TOTAL (N4_HID + N4_WQKV + N4_WO + N_ROPE)

__device__ inline void cast4(const float* in, __hip_bfloat16* out, int i) {
    float4 v = ((const float4*)in)[i];
    union { ushort4 u; __hip_bfloat16 h[4]; } o;
    o.h[0] = __float2bfloat16(v.x); o.h[1] = __float2bfloat16(v.y);
    o.h[2] = __float2bfloat16(v.z); o.h[3] = __float2bfloat16(v.w);
    ((ushort4*)out)[i] = o.u;
}

__global__ __launch_bounds__(256) void setup_kernel(const float* __restrict__ hidden,
                                                    const float* __restrict__ Wqkv,
                                                    const float* __restrict__ Wo,
                                                    __hip_bfloat16* __restrict__ hid_bf,
                                                    __hip_bfloat16* __restrict__ wqkv_bf,
                                                    __hip_bfloat16* __restrict__ wo_bf,
                                                    float2* __restrict__ tab) {
    int id = blockIdx.x * 256 + threadIdx.x;
    if (id < N4_HID) {
        cast4(hidden, hid_bf, id);
    } else if (id < N4_HID + N4_WQKV) {
        cast4(Wqkv, wqkv_bf, id - N4_HID);
    } else if (id < N4_HID + N4_WQKV + N4_WO) {
        cast4(Wo, wo_bf, id - N4_HID - N4_WQKV);
    } else if (id < SETUP_TOTAL) {
        int idx = id - (N4_HID + N4_WQKV + N4_WO);
        int t = idx >> 5, j = idx & 31;
        const float L2T_OVER_32 = 13.287712379549449f / 32.0f;  // log2(10000)/32
        float inv = exp2f(-(float)j * L2T_OVER_32);
        float s, c;
        sincosf((float)t * inv, &s, &c);
        tab[idx] = make_float2(c, s);
    }
}

// ---------------------------------------------------------------------------
// bf16 MFMA NT GEMM: C[m,n] = sum_k A[m*lda+k]*B[n*ldb+k]
// BM=BN=128, BK=64 (12 iters at K=768 -> half the barrier drains of BK=32).
// LDS tiles [128][64] staged via global_load_lds with XOR-swizzled global
// source (chunk ^ (row&7)): fragment ds_read_b128 then hits each 4-bank
// group with exactly 2 lanes -> conflict-free (2-way is free, m136).
// Epilogue: per-wave 16x72 LDS patch -> coalesced global_store_dwordx4.
// XCD-aware 1D grid: XCD (bid&7) owns m-tiles [8x,8x+8) for all n-tiles.
// Optional fused RoPE epilogue on q/k columns.
// ---------------------------------------------------------------------------
template <typename OutT>
__global__ __launch_bounds__(256) void gemm_nt_bf16(const __hip_bfloat16* __restrict__ A,
                                                    const __hip_bfloat16* __restrict__ B,
                                                    OutT* __restrict__ C,
                                                    int lda, int ldb, int ldc, int K,
                                                    const float2* __restrict__ rope_tab) {
    __shared__ __align__(16) char smem[32768];
    __hip_bfloat16* As = (__hip_bfloat16*)smem;            // [128][64]
    __hip_bfloat16* Bs = (__hip_bfloat16*)(smem + 16384);  // [128][64]

    const int tid  = threadIdx.x;
    const int lane = tid & 63;
    const int wave = tid >> 6;
    const int wr   = wave >> 1;
    const int wc   = wave & 1;
    const int fr   = lane & 15;
    const int quad = lane >> 4;

    // XCD-aware swizzle (gridM = 64 m-tiles, 8 per XCD)
    const int bid = blockIdx.x;
    const int x   = bid & 7;
    const int j   = bid >> 3;
    const int m0  = (x * 8 + (j & 7)) * 128;
    const int n0  = (j >> 3) * 128;

    f32x4 acc[4][4];
#pragma unroll
    for (int i = 0; i < 4; i++)
#pragma unroll
        for (int jj = 0; jj < 4; jj++) acc[i][jj] = (f32x4){0.f, 0.f, 0.f, 0.f};

    for (int k0 = 0; k0 < K; k0 += 64) {
        __syncthreads();
        // stage 128x64 tiles: 1024 16B tasks each; 4 insts/wave/tile.
        // task t -> LDS offset t*16B (linear: base + lane*16, required by HW);
        // global source chunk is XOR-permuted within the row.
#pragma unroll
        for (int c = 0; c < 4; c++) {
            int t = (wave * 4 + c) * 64 + lane;      // 0..1023
            int row = t >> 3, ch = t & 7;
            int gcol = (ch ^ (row & 7)) * 8;
            gl_lds16(A + (size_t)(m0 + row) * lda + k0 + gcol, As + t * 8);
            gl_lds16(B + (size_t)(n0 + row) * ldb + k0 + gcol, Bs + t * 8);
        }
        __syncthreads();

#pragma unroll
        for (int ks = 0; ks < 2; ks++) {
            bf16x8 af[4], bf_[4];
#pragma unroll
            for (int mi = 0; mi < 4; mi++) {
                int row = wr * 64 + mi * 16 + fr;
                int pos = (ks * 4 + quad) ^ (row & 7);
                af[mi] = *(const bf16x8*)(As + row * 64 + pos * 8);
            }
#pragma unroll
            for (int ni = 0; ni < 4; ni++) {
                int row = wc * 64 + ni * 16 + fr;
                int pos = (ks * 4 + quad) ^ (row & 7);
                bf_[ni] = *(const bf16x8*)(Bs + row * 64 + pos * 8);
            }
#pragma unroll
            for (int mi = 0; mi < 4; mi++)
#pragma unroll
                for (int ni = 0; ni < 4; ni++)
                    acc[mi][ni] = __builtin_amdgcn_mfma_f32_16x16x32_bf16(af[mi], bf_[ni], acc[mi][ni], 0, 0, 0);
        }
    }

    // fused RoPE: 64-col group b0 covers exactly one head; pairs (ni, ni+2)
    const int b0 = n0 + wc * 64;
    if (rope_tab != nullptr && b0 < 2 * DMODEL) {
#pragma unroll
        for (int mi = 0; mi < 4; mi++) {
#pragma unroll
            for (int r = 0; r < 4; r++) {
                int t = (m0 + wr * 64 + mi * 16 + quad * 4 + r) & (SEQ - 1);
#pragma unroll
                for (int ni = 0; ni < 2; ni++) {
                    float2 cs = rope_tab[t * 32 + ni * 16 + fr];
                    float x0 = acc[mi][ni][r], x1 = acc[mi][ni + 2][r];
                    acc[mi][ni][r]     = x0 * cs.x - x1 * cs.y;
                    acc[mi][ni + 2][r] = x0 * cs.y + x1 * cs.x;
                }
            }
        }
    }

    // ---- epilogue via per-wave LDS patch -> coalesced dwordx4 stores
    __syncthreads();   // all fragment reads done; reuse smem as patch space
    OutT* patch = (OutT*)smem + wave * (16 * 72);
    constexpr int NV = sizeof(OutT);   // uint4s per 16 cols: bf16->2, f32->4

#pragma unroll
    for (int mi = 0; mi < 4; mi++) {
#pragma unroll
        for (int ni = 0; ni < 4; ni++)
#pragma unroll
            for (int r = 0; r < 4; r++)
                to_out(&patch[(quad * 4 + r) * 72 + ni * 16 + fr], acc[mi][ni][r]);
        __syncthreads();   // intra-wave LDS ordering (uniform flow, cheap)
        {
            int prow = lane >> 2, seg = lane & 3;
            const uint4* src = (const uint4*)(patch + prow * 72 + seg * 16);
            OutT* dst = &C[(size_t)(m0 + wr * 64 + mi * 16 + prow) * ldc + b0 + seg * 16];
#pragma unroll
            for (int v = 0; v < NV; v++)
                ((uint4*)dst)[v] = src[v];
        }
        __syncthreads();
    }
}

// ---------------------------------------------------------------------------
// Sliding-window attention, one block per (b, head, 64-query tile).
// QK^T and PV via MFMA; in-register softmax via quad-group shuffles.
// Q fragments loaded directly from global (no LDS staging). K staged with
// stride 64 + XOR swizzle (conflict-free). LDS 48 KB -> 3 blocks/CU.
// ---------------------------------------------------------------------------
#define PLD  192

__global__ __launch_bounds__(256) void attn_kernel(const __hip_bfloat16* __restrict__ qkv,
                                                   const int* __restrict__ mask,
                                                   __hip_bfloat16* __restrict__ attn) {
    __shared__ __align__(16) char smem[49152];
    __hip_bfloat16* Ks = (__hip_bfloat16*)smem;            // [192][64] swizzled
    __hip_bfloat16* Pb = (__hip_bfloat16*)smem;            // [64][192] swizzled (aliases Ks)
    __hip_bfloat16* Vt = (__hip_bfloat16*)(smem + 24576);  // [64][192] swizzled

    const int tid  = threadIdx.x;
    const int lane = tid & 63;
    const int wave = tid >> 6;
    const int fr   = lane & 15;
    const int quad = lane >> 4;

    // XCD-aware swizzle: 1536 blocks = 8 XCDs x 192
    const int bid  = blockIdx.x;
    const int x    = bid & 7;
    const int j    = bid >> 3;                 // 0..191
    const int b    = x >> 1;
    const int q0   = ((x & 1) * 16 + (j & 15)) * 64;
    const int head = j >> 4;                   // 0..11

    const int klo = max(0, q0 - WIN);
    const int khi = min(SEQ, q0 + 64 + WIN);
    const int nk  = khi - klo;     // 128 or 192
    const int nt  = nk >> 4;       // 8 or 12
    const int nkc = nk >> 5;       // 4 or 6

    const size_t rowbase = (size_t)(b * SEQ) * QKV_LD + head * HDIM;

    // ---- stage K [nk][64] XOR-swizzled: up to 1536 uint4 tasks
    for (int task = tid; task < nk * 8; task += 256) {
        int row = task >> 3, g = task & 7;
        uint4 v = *(const uint4*)(qkv + rowbase + (size_t)(klo + row) * QKV_LD + DMODEL + g * 8);
        *(uint4*)(Ks + row * 64 + (g ^ (row & 7)) * 8) = v;
    }
    // ---- stage V transposed [64][nk], XOR-swizzled chunks of 8
    {
        int h = lane;
        const __hip_bfloat16* vb = qkv + rowbase + 2 * DMODEL + h;
        int ng = nk >> 3;
        for (int g = wave; g < ng; g += 4) {
            unsigned int u0, u1, u2, u3;
            {
                unsigned short a0 = *(const unsigned short*)(vb + (size_t)(klo + g * 8 + 0) * QKV_LD);
                unsigned short a1 = *(const unsigned short*)(vb + (size_t)(klo + g * 8 + 1) * QKV_LD);
                unsigned short a2 = *(const unsigned short*)(vb + (size_t)(klo + g * 8 + 2) * QKV_LD);
                unsigned short a3 = *(const unsigned short*)(vb + (size_t)(klo + g * 8 + 3) * QKV_LD);
                unsigned short a4 = *(const unsigned short*)(vb + (size_t)(klo + g * 8 + 4) * QKV_LD);
                unsigned short a5 = *(const unsigned short*)(vb + (size_t)(klo + g * 8 + 5) * QKV_LD);
                unsigned short a6 = *(const unsigned short*)(vb + (size_t)(klo + g * 8 + 6) * QKV_LD);
                unsigned short a7 = *(const unsigned short*)(vb + (size_t)(klo + g * 8 + 7) * QKV_LD);
                u0 = (unsigned int)a0 | ((unsigned int)a1 << 16);
                u1 = (unsigned int)a2 | ((unsigned int)a3 << 16);
                u2 = (unsigned int)a4 | ((unsigned int)a5 << 16);
                u3 = (unsigned int)a6 | ((unsigned int)a7 << 16);
            }
            int cs = g ^ (h & 7);
            *(uint4*)(Vt + h * PLD + cs * 8) = make_uint4(u0, u1, u2, u3);
        }
    }

    // ---- Q fragments direct from global (A-layout: row=fr, k=quad*8+j)
    const int qrow0 = q0 + wave * 16;
    bf16x8 aq0 = *(const bf16x8*)(qkv + rowbase + (size_t)(qrow0 + fr) * QKV_LD + quad * 8);
    bf16x8 aq1 = *(const bf16x8*)(qkv + rowbase + (size_t)(qrow0 + fr) * QKV_LD + 32 + quad * 8);

    const int* mb = mask + b * SEQ;
    int mq[4];
#pragma unroll
    for (int r = 0; r < 4; r++) mq[r] = mb[qrow0 + quad * 4 + r];

    __syncthreads();

    // ---- QK^T via MFMA over key tiles
    f32x4 sc[12];
#pragma unroll
    for (int kt = 0; kt < 12; kt++) sc[kt] = (f32x4){-1e30f, -1e30f, -1e30f, -1e30f};

#pragma unroll
    for (int kt = 0; kt < 12; kt++) {
        if (kt < nt) {
            int krow = kt * 16 + fr;
            int kg = klo + krow;
            int p0 = (quad) ^ (krow & 7);
            int p1 = (4 + quad) ^ (krow & 7);
            bf16x8 bk0 = *(const bf16x8*)(Ks + krow * 64 + p0 * 8);
            bf16x8 bk1 = *(const bf16x8*)(Ks + krow * 64 + p1 * 8);
            f32x4 a = (f32x4){0.f, 0.f, 0.f, 0.f};
            a = __builtin_amdgcn_mfma_f32_16x16x32_bf16(aq0, bk0, a, 0, 0, 0);
            a = __builtin_amdgcn_mfma_f32_16x16x32_bf16(aq1, bk1, a, 0, 0, 0);
            int mk = mb[kg];
            f32x4 s;
#pragma unroll
            for (int r = 0; r < 4; r++) {
                int qg = qrow0 + quad * 4 + r;
                bool ok = (abs(qg - kg) <= WIN) && (mk != 0) && (mq[r] != 0);
                s[r] = ok ? a[r] * 0.125f : -1e30f;
            }
            sc[kt] = s;
        }
    }

    // ---- in-register softmax: reduce across fr lanes (same quad group)
    f32x4 mx = sc[0];
#pragma unroll
    for (int kt = 1; kt < 12; kt++)
#pragma unroll
        for (int r = 0; r < 4; r++) mx[r] = fmaxf(mx[r], sc[kt][r]);
#pragma unroll
    for (int off = 8; off >= 1; off >>= 1)
#pragma unroll
        for (int r = 0; r < 4; r++) mx[r] = fmaxf(mx[r], __shfl_xor(mx[r], off));

    f32x4 sum = (f32x4){0.f, 0.f, 0.f, 0.f};
#pragma unroll
    for (int kt = 0; kt < 12; kt++)
#pragma unroll
        for (int r = 0; r < 4; r++) {
            float e = __expf(sc[kt][r] - mx[r]);
            sc[kt][r] = e;
            sum[r] += e;
        }
#pragma unroll
    for (int off = 8; off >= 1; off >>= 1)
#pragma unroll
        for (int r = 0; r < 4; r++) sum[r] += __shfl_xor(sum[r], off);
    f32x4 rs;
#pragma unroll
    for (int r = 0; r < 4; r++) rs[r] = 1.0f / sum[r];

    // ---- write P (bf16, A-layout-friendly, swizzled) into Ks space
    __syncthreads();   // all waves done reading Ks
#pragma unroll
    for (int kt = 0; kt < 12; kt++) {
        if (kt < nt) {
#pragma unroll
            for (int r = 0; r < 4; r++) {
                int prow = wave * 16 + quad * 4 + r;
                int c = kt * 2 + (fr >> 3);
                int cs = c ^ (prow & 7);
                Pb[prow * PLD + cs * 8 + (fr & 7)] = __float2bfloat16(sc[kt][r] * rs[r]);
            }
        }
    }
    __syncthreads();

    // ---- PV via MFMA: O[16q][64h] per wave
    f32x4 o[4];
#pragma unroll
    for (int ht = 0; ht < 4; ht++) o[ht] = (f32x4){0.f, 0.f, 0.f, 0.f};

#pragma unroll
    for (int kc = 0; kc < 6; kc++) {
        if (kc < nkc) {
            int cs = (kc * 4 + quad) ^ (fr & 7);
            bf16x8 ap = *(const bf16x8*)(Pb + (wave * 16 + fr) * PLD + cs * 8);
#pragma unroll
            for (int ht = 0; ht < 4; ht++) {
                bf16x8 bv = *(const bf16x8*)(Vt + (ht * 16 + fr) * PLD + cs * 8);
                o[ht] = __builtin_amdgcn_mfma_f32_16x16x32_bf16(ap, bv, o[ht], 0, 0, 0);
            }
        }
    }

    // ---- store O (bf16) to attn [B*T, 768]
    __hip_bfloat16* ob = attn + (size_t)(b * SEQ + qrow0) * DMODEL + head * HDIM;
#pragma unroll
    for (int r = 0; r < 4; r++)
#pragma unroll
        for (int ht = 0; ht < 4; ht++)
            ob[(size_t)(quad * 4 + r) * DMODEL + ht * 16 + fr] = __float2bfloat16(o[ht][r]);
}

// ---------------------------------------------------------------------------
extern "C" void kernel_launch(void* const* d_in, const int* in_sizes, int n_in,
                              void* d_out, int out_size, void* d_ws, size_t ws_size,
                              hipStream_t stream) {
    const float* hidden = (const float*)d_in[0];
    const int*   mask   = (const int*)d_in[1];
    const float* Wqkv   = (const float*)d_in[2];
    const float* Wo     = (const float*)d_in[3];
    float* out = (float*)d_out;

    char* w = (char*)d_ws;
    __hip_bfloat16* qkv_bf  = (__hip_bfloat16*)(w);              // 37,748,736
    __hip_bfloat16* hid_bf  = (__hip_bfloat16*)(w + 37748736);   // 12,582,912
    __hip_bfloat16* wqkv_bf = (__hip_bfloat16*)(w + 50331648);   //  3,538,944
    __hip_bfloat16* wo_bf   = (__hip_bfloat16*)(w + 53870592);   //  1,179,648
    __hip_bfloat16* attn_bf = (__hip_bfloat16*)(w + 55050240);   // 12,582,912
    float2*         tab     = (float2*)(w + 67633152);           //    524,288

    // 0) fused setup: casts + rope table (one launch)
    setup_kernel<<<SETUP_TOTAL / 256, 256, 0, stream>>>(hidden, Wqkv, Wo,
                                                        hid_bf, wqkv_bf, wo_bf, tab);

    // 1) QKV projection + fused RoPE (XCD-swizzled 1D grid: 18 n-tiles x 64 m-tiles)
    gemm_nt_bf16<__hip_bfloat16><<<18 * 64, 256, 0, stream>>>(hid_bf, wqkv_bf, qkv_bf,
                                                              DMODEL, DMODEL, QKV_LD, DMODEL, tab);

    // 2) sliding-window attention (XCD-swizzled 1D grid)
    attn_kernel<<<(SEQ / 64) * NHEADS * BATCH, 256, 0, stream>>>(qkv_bf, mask, attn_bf);

    // 3) output projection (6 n-tiles x 64 m-tiles)
    gemm_nt_bf16<float><<<6 * 64, 256, 0, stream>>>(attn_bf, wo_bf, out,
                                                    DMODEL, DMODEL, DMODEL, DMODEL, nullptr);
}

// Round 6
// 182.343 us; speedup vs baseline: 6.4006x; 1.0537x over previous
//
#include <hip/hip_runtime.h>
#include <hip/hip_bf16.h>
#include <math.h>

// Problem constants (ModernBERT attention)
#define BATCH 4
#define SEQ   2048
#define DMODEL 768
#define NHEADS 12
#define HDIM  64
#define WIN   64          // window each side
#define QKV_LD 2304       // 3*DMODEL

typedef __attribute__((ext_vector_type(8))) short bf16x8;  // 8 bf16 = 4 VGPRs
typedef __attribute__((ext_vector_type(4))) float f32x4;

typedef __attribute__((address_space(1))) const unsigned int guint;
typedef __attribute__((address_space(3))) unsigned int luint;

__device__ inline void gl_lds16(const __hip_bfloat16* g, __hip_bfloat16* l) {
    __builtin_amdgcn_global_load_lds((guint*)g, (luint*)l, 16, 0, 0);
}

__device__ inline void to_out(float* p, float v) { *p = v; }
__device__ inline void to_out(__hip_bfloat16* p, float v) { *p = __float2bfloat16(v); }

// ---------------------------------------------------------------------------
// fused setup: cast hidden/Wqkv/Wo to bf16 + build rope cos/sin table.
// ---------------------------------------------------------------------------
#define N4_HID  (BATCH * SEQ * DMODEL / 4)     // 1,572,864
#define N4_WQKV (QKV_LD * DMODEL / 4)          //   442,368
#define N4_WO   (DMODEL * DMODEL / 4)          //   147,456
#define N_ROPE  (SEQ * 32)                     //    65,536
#define SETUP_TOTAL (N4_HID + N4_WQKV + N4_WO + N_ROPE)

__device__ inline void cast4(const float* in, __hip_bfloat16* out, int i) {
    float4 v = ((const float4*)in)[i];
    union { ushort4 u; __hip_bfloat16 h[4]; } o;
    o.h[0] = __float2bfloat16(v.x); o.h[1] = __float2bfloat16(v.y);
    o.h[2] = __float2bfloat16(v.z); o.h[3] = __float2bfloat16(v.w);
    ((ushort4*)out)[i] = o.u;
}

__global__ __launch_bounds__(256) void setup_kernel(const float* __restrict__ hidden,
                                                    const float* __restrict__ Wqkv,
                                                    const float* __restrict__ Wo,
                                                    __hip_bfloat16* __restrict__ hid_bf,
                                                    __hip_bfloat16* __restrict__ wqkv_bf,
                                                    __hip_bfloat16* __restrict__ wo_bf,
                                                    float2* __restrict__ tab) {
    int id = blockIdx.x * 256 + threadIdx.x;
    if (id < N4_HID) {
        cast4(hidden, hid_bf, id);
    } else if (id < N4_HID + N4_WQKV) {
        cast4(Wqkv, wqkv_bf, id - N4_HID);
    } else if (id < N4_HID + N4_WQKV + N4_WO) {
        cast4(Wo, wo_bf, id - N4_HID - N4_WQKV);
    } else if (id < SETUP_TOTAL) {
        int idx = id - (N4_HID + N4_WQKV + N4_WO);
        int t = idx >> 5, j = idx & 31;
        const float L2T_OVER_32 = 13.287712379549449f / 32.0f;  // log2(10000)/32
        float inv = exp2f(-(float)j * L2T_OVER_32);
        float s, c;
        sincosf((float)t * inv, &s, &c);
        tab[idx] = make_float2(c, s);
    }
}

// ---------------------------------------------------------------------------
// bf16 MFMA NT GEMM: C[m,n] = sum_k A[m*lda+k]*B[n*ldb+k]
// BM=128, BN=64*NWN (NWN=2 -> 128x128, 2x2 waves; NWN=1 -> 128x64, 4x1 waves).
// BK=64, global_load_lds staging with XOR-swizzled source chunks -> fragment
// ds_read_b128 conflict-free (verified R5: conflicts 3.5M -> 147K).
// Epilogue: direct per-lane scalar stores, NO barriers (R5's LDS-patch
// epilogue regressed 57->68 us from its 8 block barriers).
// XCD-aware 1D grid: XCD (bid&7) owns m-tiles [8x,8x+8) for all n-tiles.
// Optional fused RoPE epilogue on q/k columns (rope_tab != nullptr).
// ---------------------------------------------------------------------------
template <typename OutT, int NWN>
__global__ __launch_bounds__(256) void gemm_nt_bf16(const __hip_bfloat16* __restrict__ A,
                                                    const __hip_bfloat16* __restrict__ B,
                                                    OutT* __restrict__ C,
                                                    int lda, int ldb, int ldc, int K,
                                                    const float2* __restrict__ rope_tab) {
    constexpr int BN  = 64 * NWN;     // 128 or 64
    constexpr int NWM = 4 / NWN;      // 2 or 4
    constexpr int WM  = 128 / NWM;    // 64 or 32
    constexpr int MI  = WM / 16;      // 4 or 2

    __shared__ __align__(16) __hip_bfloat16 As[128 * 64];   // 16 KB
    __shared__ __align__(16) __hip_bfloat16 Bs[BN * 64];    // 16 or 8 KB

    const int tid  = threadIdx.x;
    const int lane = tid & 63;
    const int wave = tid >> 6;
    const int wm   = wave / NWN;
    const int wn   = wave % NWN;
    const int fr   = lane & 15;
    const int quad = lane >> 4;

    // XCD-aware swizzle (gridM = 64 m-tiles, 8 per XCD)
    const int bid = blockIdx.x;
    const int x   = bid & 7;
    const int j   = bid >> 3;
    const int m0  = (x * 8 + (j & 7)) * 128;
    const int n0  = (j >> 3) * BN;

    f32x4 acc[MI][4];
#pragma unroll
    for (int i = 0; i < MI; i++)
#pragma unroll
        for (int jj = 0; jj < 4; jj++) acc[i][jj] = (f32x4){0.f, 0.f, 0.f, 0.f};

    for (int k0 = 0; k0 < K; k0 += 64) {
        __syncthreads();
        // A tile 128x64 = 1024 16B-chunks, 4 insts/wave; B tile BN x 64.
        // LDS addr = t*16 (lane-linear, required by global_load_lds);
        // global source chunk XOR-permuted within the row.
#pragma unroll
        for (int c = 0; c < 4; c++) {
            int t = (wave * 4 + c) * 64 + lane;      // 0..1023
            int row = t >> 3, ch = t & 7;
            int gcol = (ch ^ (row & 7)) * 8;
            gl_lds16(A + (size_t)(m0 + row) * lda + k0 + gcol, As + t * 8);
        }
#pragma unroll
        for (int c = 0; c < 2 * NWN; c++) {
            int t = (wave * 2 * NWN + c) * 64 + lane;
            int row = t >> 3, ch = t & 7;
            int gcol = (ch ^ (row & 7)) * 8;
            gl_lds16(B + (size_t)(n0 + row) * ldb + k0 + gcol, Bs + t * 8);
        }
        __syncthreads();

#pragma unroll
        for (int ks = 0; ks < 2; ks++) {
            bf16x8 af[MI], bf_[4];
#pragma unroll
            for (int mi = 0; mi < MI; mi++) {
                int row = wm * WM + mi * 16 + fr;
                int pos = (ks * 4 + quad) ^ (row & 7);
                af[mi] = *(const bf16x8*)(As + row * 64 + pos * 8);
            }
#pragma unroll
            for (int ni = 0; ni < 4; ni++) {
                int row = wn * 64 + ni * 16 + fr;
                int pos = (ks * 4 + quad) ^ (row & 7);
                bf_[ni] = *(const bf16x8*)(Bs + row * 64 + pos * 8);
            }
#pragma unroll
            for (int mi = 0; mi < MI; mi++)
#pragma unroll
                for (int ni = 0; ni < 4; ni++)
                    acc[mi][ni] = __builtin_amdgcn_mfma_f32_16x16x32_bf16(af[mi], bf_[ni], acc[mi][ni], 0, 0, 0);
        }
    }

    // fused RoPE: 64-col group b0 covers exactly one head; pairs (ni, ni+2)
    const int b0 = n0 + wn * 64;
    if (rope_tab != nullptr && b0 < 2 * DMODEL) {
#pragma unroll
        for (int mi = 0; mi < MI; mi++) {
#pragma unroll
            for (int r = 0; r < 4; r++) {
                int t = (m0 + wm * WM + mi * 16 + quad * 4 + r) & (SEQ - 1);
#pragma unroll
                for (int ni = 0; ni < 2; ni++) {
                    float2 cs = rope_tab[t * 32 + ni * 16 + fr];
                    float x0 = acc[mi][ni][r], x1 = acc[mi][ni + 2][r];
                    acc[mi][ni][r]     = x0 * cs.x - x1 * cs.y;
                    acc[mi][ni + 2][r] = x0 * cs.y + x1 * cs.x;
                }
            }
        }
    }

    // direct scalar-store epilogue (no barriers)
#pragma unroll
    for (int mi = 0; mi < MI; mi++)
#pragma unroll
        for (int ni = 0; ni < 4; ni++) {
            f32x4 v = acc[mi][ni];
            int gc = b0 + ni * 16 + fr;
            size_t rbase = (size_t)(m0 + wm * WM + mi * 16 + quad * 4);
#pragma unroll
            for (int r = 0; r < 4; r++)
                to_out(&C[(rbase + r) * ldc + gc], v[r]);
        }
}

// ---------------------------------------------------------------------------
// Sliding-window attention, one block per (b, head, 64-query tile).
// QK^T and PV via MFMA; in-register softmax via quad-group shuffles.
// Q fragments loaded directly from global. K staged stride 64 + XOR swizzle.
// LDS 48 KB -> 3 blocks/CU.
// ---------------------------------------------------------------------------
#define PLD  192

__global__ __launch_bounds__(256) void attn_kernel(const __hip_bfloat16* __restrict__ qkv,
                                                   const int* __restrict__ mask,
                                                   __hip_bfloat16* __restrict__ attn) {
    __shared__ __align__(16) char smem[49152];
    __hip_bfloat16* Ks = (__hip_bfloat16*)smem;            // [192][64] swizzled
    __hip_bfloat16* Pb = (__hip_bfloat16*)smem;            // [64][192] swizzled (aliases Ks)
    __hip_bfloat16* Vt = (__hip_bfloat16*)(smem + 24576);  // [64][192] swizzled

    const int tid  = threadIdx.x;
    const int lane = tid & 63;
    const int wave = tid >> 6;
    const int fr   = lane & 15;
    const int quad = lane >> 4;

    // XCD-aware swizzle: 1536 blocks = 8 XCDs x 192
    const int bid  = blockIdx.x;
    const int x    = bid & 7;
    const int j    = bid >> 3;                 // 0..191
    const int b    = x >> 1;
    const int q0   = ((x & 1) * 16 + (j & 15)) * 64;
    const int head = j >> 4;                   // 0..11

    const int klo = max(0, q0 - WIN);
    const int khi = min(SEQ, q0 + 64 + WIN);
    const int nk  = khi - klo;     // 128 or 192
    const int nt  = nk >> 4;       // 8 or 12
    const int nkc = nk >> 5;       // 4 or 6

    const size_t rowbase = (size_t)(b * SEQ) * QKV_LD + head * HDIM;

    // ---- stage K [nk][64] XOR-swizzled: up to 1536 uint4 tasks
    for (int task = tid; task < nk * 8; task += 256) {
        int row = task >> 3, g = task & 7;
        uint4 v = *(const uint4*)(qkv + rowbase + (size_t)(klo + row) * QKV_LD + DMODEL + g * 8);
        *(uint4*)(Ks + row * 64 + (g ^ (row & 7)) * 8) = v;
    }
    // ---- stage V transposed [64][nk], XOR-swizzled chunks of 8
    {
        int h = lane;
        const __hip_bfloat16* vb = qkv + rowbase + 2 * DMODEL + h;
        int ng = nk >> 3;
        for (int g = wave; g < ng; g += 4) {
            unsigned int u0, u1, u2, u3;
            {
                unsigned short a0 = *(const unsigned short*)(vb + (size_t)(klo + g * 8 + 0) * QKV_LD);
                unsigned short a1 = *(const unsigned short*)(vb + (size_t)(klo + g * 8 + 1) * QKV_LD);
                unsigned short a2 = *(const unsigned short*)(vb + (size_t)(klo + g * 8 + 2) * QKV_LD);
                unsigned short a3 = *(const unsigned short*)(vb + (size_t)(klo + g * 8 + 3) * QKV_LD);
                unsigned short a4 = *(const unsigned short*)(vb + (size_t)(klo + g * 8 + 4) * QKV_LD);
                unsigned short a5 = *(const unsigned short*)(vb + (size_t)(klo + g * 8 + 5) * QKV_LD);
                unsigned short a6 = *(const unsigned short*)(vb + (size_t)(klo + g * 8 + 6) * QKV_LD);
                unsigned short a7 = *(const unsigned short*)(vb + (size_t)(klo + g * 8 + 7) * QKV_LD);
                u0 = (unsigned int)a0 | ((unsigned int)a1 << 16);
                u1 = (unsigned int)a2 | ((unsigned int)a3 << 16);
                u2 = (unsigned int)a4 | ((unsigned int)a5 << 16);
                u3 = (unsigned int)a6 | ((unsigned int)a7 << 16);
            }
            int cs = g ^ (h & 7);
            *(uint4*)(Vt + h * PLD + cs * 8) = make_uint4(u0, u1, u2, u3);
        }
    }

    // ---- Q fragments direct from global (A-layout: row=fr, k=quad*8+j)
    const int qrow0 = q0 + wave * 16;
    bf16x8 aq0 = *(const bf16x8*)(qkv + rowbase + (size_t)(qrow0 + fr) * QKV_LD + quad * 8);
    bf16x8 aq1 = *(const bf16x8*)(qkv + rowbase + (size_t)(qrow0 + fr) * QKV_LD + 32 + quad * 8);

    const int* mb = mask + b * SEQ;
    int mq[4];
#pragma unroll
    for (int r = 0; r < 4; r++) mq[r] = mb[qrow0 + quad * 4 + r];

    __syncthreads();

    // ---- QK^T via MFMA over key tiles
    f32x4 sc[12];
#pragma unroll
    for (int kt = 0; kt < 12; kt++) sc[kt] = (f32x4){-1e30f, -1e30f, -1e30f, -1e30f};

#pragma unroll
    for (int kt = 0; kt < 12; kt++) {
        if (kt < nt) {
            int krow = kt * 16 + fr;
            int kg = klo + krow;
            int p0 = (quad) ^ (krow & 7);
            int p1 = (4 + quad) ^ (krow & 7);
            bf16x8 bk0 = *(const bf16x8*)(Ks + krow * 64 + p0 * 8);
            bf16x8 bk1 = *(const bf16x8*)(Ks + krow * 64 + p1 * 8);
            f32x4 a = (f32x4){0.f, 0.f, 0.f, 0.f};
            a = __builtin_amdgcn_mfma_f32_16x16x32_bf16(aq0, bk0, a, 0, 0, 0);
            a = __builtin_amdgcn_mfma_f32_16x16x32_bf16(aq1, bk1, a, 0, 0, 0);
            int mk = mb[kg];
            f32x4 s;
#pragma unroll
            for (int r = 0; r < 4; r++) {
                int qg = qrow0 + quad * 4 + r;
                bool ok = (abs(qg - kg) <= WIN) && (mk != 0) && (mq[r] != 0);
                s[r] = ok ? a[r] * 0.125f : -1e30f;
            }
            sc[kt] = s;
        }
    }

    // ---- in-register softmax: reduce across fr lanes (same quad group)
    f32x4 mx = sc[0];
#pragma unroll
    for (int kt = 1; kt < 12; kt++)
#pragma unroll
        for (int r = 0; r < 4; r++) mx[r] = fmaxf(mx[r], sc[kt][r]);
#pragma unroll
    for (int off = 8; off >= 1; off >>= 1)
#pragma unroll
        for (int r = 0; r < 4; r++) mx[r] = fmaxf(mx[r], __shfl_xor(mx[r], off));

    f32x4 sum = (f32x4){0.f, 0.f, 0.f, 0.f};
#pragma unroll
    for (int kt = 0; kt < 12; kt++)
#pragma unroll
        for (int r = 0; r < 4; r++) {
            float e = __expf(sc[kt][r] - mx[r]);
            sc[kt][r] = e;
            sum[r] += e;
        }
#pragma unroll
    for (int off = 8; off >= 1; off >>= 1)
#pragma unroll
        for (int r = 0; r < 4; r++) sum[r] += __shfl_xor(sum[r], off);
    f32x4 rs;
#pragma unroll
    for (int r = 0; r < 4; r++) rs[r] = 1.0f / sum[r];

    // ---- write P (bf16, A-layout-friendly, swizzled) into Ks space
    __syncthreads();   // all waves done reading Ks
#pragma unroll
    for (int kt = 0; kt < 12; kt++) {
        if (kt < nt) {
#pragma unroll
            for (int r = 0; r < 4; r++) {
                int prow = wave * 16 + quad * 4 + r;
                int c = kt * 2 + (fr >> 3);
                int cs = c ^ (prow & 7);
                Pb[prow * PLD + cs * 8 + (fr & 7)] = __float2bfloat16(sc[kt][r] * rs[r]);
            }
        }
    }
    __syncthreads();

    // ---- PV via MFMA: O[16q][64h] per wave
    f32x4 o[4];
#pragma unroll
    for (int ht = 0; ht < 4; ht++) o[ht] = (f32x4){0.f, 0.f, 0.f, 0.f};

#pragma unroll
    for (int kc = 0; kc < 6; kc++) {
        if (kc < nkc) {
            int cs = (kc * 4 + quad) ^ (fr & 7);
            bf16x8 ap = *(const bf16x8*)(Pb + (wave * 16 + fr) * PLD + cs * 8);
#pragma unroll
            for (int ht = 0; ht < 4; ht++) {
                bf16x8 bv = *(const bf16x8*)(Vt + (ht * 16 + fr) * PLD + cs * 8);
                o[ht] = __builtin_amdgcn_mfma_f32_16x16x32_bf16(ap, bv, o[ht], 0, 0, 0);
            }
        }
    }

    // ---- store O (bf16) to attn [B*T, 768]
    __hip_bfloat16* ob = attn + (size_t)(b * SEQ + qrow0) * DMODEL + head * HDIM;
#pragma unroll
    for (int r = 0; r < 4; r++)
#pragma unroll
        for (int ht = 0; ht < 4; ht++)
            ob[(size_t)(quad * 4 + r) * DMODEL + ht * 16 + fr] = __float2bfloat16(o[ht][r]);
}

// ---------------------------------------------------------------------------
extern "C" void kernel_launch(void* const* d_in, const int* in_sizes, int n_in,
                              void* d_out, int out_size, void* d_ws, size_t ws_size,
                              hipStream_t stream) {
    const float* hidden = (const float*)d_in[0];
    const int*   mask   = (const int*)d_in[1];
    const float* Wqkv   = (const float*)d_in[2];
    const float* Wo     = (const float*)d_in[3];
    float* out = (float*)d_out;

    char* w = (char*)d_ws;
    __hip_bfloat16* qkv_bf  = (__hip_bfloat16*)(w);              // 37,748,736
    __hip_bfloat16* hid_bf  = (__hip_bfloat16*)(w + 37748736);   // 12,582,912
    __hip_bfloat16* wqkv_bf = (__hip_bfloat16*)(w + 50331648);   //  3,538,944
    __hip_bfloat16* wo_bf   = (__hip_bfloat16*)(w + 53870592);   //  1,179,648
    __hip_bfloat16* attn_bf = (__hip_bfloat16*)(w + 55050240);   // 12,582,912
    float2*         tab     = (float2*)(w + 67633152);           //    524,288

    // 0) fused setup: casts + rope table (one launch)
    setup_kernel<<<SETUP_TOTAL / 256, 256, 0, stream>>>(hidden, Wqkv, Wo,
                                                        hid_bf, wqkv_bf, wo_bf, tab);

    // 1) QKV projection + fused RoPE (128x128 tiles, 18 n-tiles x 64 m-tiles)
    gemm_nt_bf16<__hip_bfloat16, 2><<<18 * 64, 256, 0, stream>>>(hid_bf, wqkv_bf, qkv_bf,
                                                                 DMODEL, DMODEL, QKV_LD, DMODEL, tab);

    // 2) sliding-window attention (XCD-swizzled 1D grid)
    attn_kernel<<<(SEQ / 64) * NHEADS * BATCH, 256, 0, stream>>>(qkv_bf, mask, attn_bf);

    // 3) output projection (128x64 tiles -> 768 blocks = 3 blocks/CU)
    gemm_nt_bf16<float, 1><<<12 * 64, 256, 0, stream>>>(attn_bf, wo_bf, out,
                                                        DMODEL, DMODEL, DMODEL, DMODEL, nullptr);
}